// Round 8
// baseline (261.855 us; speedup 1.0000x reference)
//
#include <hip/hip_runtime.h>
#include <math.h>

typedef unsigned short u16;
typedef unsigned int u32;

#define N_ROWS 8192
#define DDIM 512
#define HDIM 1024
#define ODIM 512
#define NEXP 8
#define MAXPAIRS (N_ROWS * 2)          // 16384
#define MAXPOS (MAXPAIRS + NEXP * 128) // 17408 (per-expert segments 128-aligned)
#define MAXTILES (MAXPOS / 128)        // 136

// small-region word indices (in d_ws)
#define SM_CNT 0   // 8 ints: expert lengths
#define SM_CUR 8   // 8 ints: scatter cursors
#define SM_AOFF 16 // 9 ints: aligned bucket offsets
#define SM_GSUM 32 // 8 floats: sum of gates per expert
#define SM_LSUM 40 // 8 floats: sum of load_probs per expert
#define SM_WORDS 64

using short8 = __attribute__((ext_vector_type(8))) short;
using float4v = __attribute__((ext_vector_type(4))) float;

__device__ __forceinline__ u16 f2bf(float f) {
    union { float f; u32 u; } v; v.f = f;
    u32 u = v.u;
    return (u16)((u + 0x7fffu + ((u >> 16) & 1u)) >> 16);
}

// async global->LDS, 16B per lane; HW places lane i at lds_base + i*16
__device__ __forceinline__ void async_copy16(u16* lds, const u16* g) {
    __builtin_amdgcn_global_load_lds(
        (const __attribute__((address_space(1))) void*)g,
        (__attribute__((address_space(3))) void*)lds, 16, 0, 0);
}

// ---------------- init1: zero small + zeropage ----------------
__global__ __launch_bounds__(512) void init1_kernel(int* small, float* zeropage) {
    int i = threadIdx.x;
    if (i < SM_WORDS) small[i] = 0;
    zeropage[i] = 0.f; // 512 floats
}

// ---------------- combo: gating + W1 convert + ow transpose + bucket init + W2 convert ----------------
#define W1CONV_BLOCKS 4096 // (8*1024*512/4) / 256
#define GATE_BLOCKS 512    // N_ROWS/16
#define OWT_BLOCKS 256
#define BUCKET_BLOCKS 68
#define W2CONV_BLOCKS 2048 // (8*512*1024/4) float4s / 512 per block
__global__ __launch_bounds__(256) void combo_kernel(
    const float* __restrict__ x, const float* __restrict__ noise,
    const float* __restrict__ norm_w, const float* __restrict__ norm_b,
    const float* __restrict__ w_gate, const float* __restrict__ w_noise,
    const float* __restrict__ W1, const float* __restrict__ ow,
    const float* __restrict__ W2,
    u16* __restrict__ xnorm_bf, u16* __restrict__ x_bf,
    int* __restrict__ pair_expert, float* __restrict__ pair_gate,
    u16* __restrict__ W1b, u16* __restrict__ owT, u16* __restrict__ W2b,
    int* __restrict__ small, int* __restrict__ bucket_rows)
{
    __shared__ __align__(16) float sh[NEXP * DDIM * 2 + 64];
    int b = blockIdx.x, tid = threadIdx.x;

    if (b >= GATE_BLOCKS) {
        int cb = b - GATE_BLOCKS;
        if (cb < W1CONV_BLOCKS) {
            size_t i = (size_t)cb * 256 + tid;
            float4 v = ((const float4*)W1)[i];
            ushort4 o;
            o.x = f2bf(v.x); o.y = f2bf(v.y); o.z = f2bf(v.z); o.w = f2bf(v.w);
            ((ushort4*)W1b)[i] = o;
        } else if (cb < W1CONV_BLOCKS + OWT_BLOCKS) {
            float (*tile)[33] = (float(*)[33])sh;
            int t = cb - W1CONV_BLOCKS;
            int bx = (t & 15) * 32, by = (t >> 4) * 32;
            int tx = tid & 31, ty = tid >> 5; // 32 x 8
            for (int r = ty; r < 32; r += 8) tile[r][tx] = ow[(size_t)(by + r) * ODIM + bx + tx];
            __syncthreads();
            for (int r = ty; r < 32; r += 8) owT[(size_t)(bx + r) * DDIM + by + tx] = f2bf(tile[tx][r]);
        } else if (cb < W1CONV_BLOCKS + OWT_BLOCKS + BUCKET_BLOCKS) {
            int i = (cb - W1CONV_BLOCKS - OWT_BLOCKS) * 256 + tid;
            if (i < MAXPOS) bucket_rows[i] = -1;
        } else { // W2 convert: 2048 blocks x 512 float4s
            int j = cb - W1CONV_BLOCKS - OWT_BLOCKS - BUCKET_BLOCKS;
            size_t i = (size_t)j * 512 + tid;
#pragma unroll
            for (int t = 0; t < 2; t++, i += 256) {
                float4 v = ((const float4*)W2)[i];
                ushort4 o;
                o.x = f2bf(v.x); o.y = f2bf(v.y); o.z = f2bf(v.z); o.w = f2bf(v.w);
                ((ushort4*)W2b)[i] = o;
            }
        }
        return;
    }

    // ---- gating body (block b of 512) ----
    float* wgT = sh;                   // [e][d] transposed -> conflict-free reads
    float* wnT = sh + NEXP * DDIM;
    float* blk_g = sh + 2 * NEXP * DDIM;
    float* blk_l = blk_g + NEXP;
    int* blk_c = (int*)(blk_l + NEXP);
    float* smf = (float*)small;

    for (int i = tid; i < NEXP * DDIM; i += 256) {
        int d = i >> 3, e = i & 7;
        wgT[e * DDIM + d] = w_gate[i];
        wnT[e * DDIM + d] = w_noise[i];
    }
    if (tid < NEXP) { blk_g[tid] = 0.f; blk_l[tid] = 0.f; blk_c[tid] = 0; }
    __syncthreads();

    int wave = tid >> 6, lane = tid & 63;
    float nw[8], nb[8];
#pragma unroll
    for (int j = 0; j < 8; j++) { nw[j] = norm_w[j * 64 + lane]; nb[j] = norm_b[j * 64 + lane]; }

    for (int r = 0; r < 4; ++r) {
        int row = b * 16 + wave * 4 + r;
        const float* xr = x + (size_t)row * DDIM;
        float xv[8], s = 0.f, s2 = 0.f;
#pragma unroll
        for (int j = 0; j < 8; j++) { float v = xr[j * 64 + lane]; xv[j] = v; s += v; s2 += v * v; }
#pragma unroll
        for (int o = 32; o; o >>= 1) { s += __shfl_xor(s, o, 64); s2 += __shfl_xor(s2, o, 64); }
        float mu = s * (1.f / DDIM);
        float var = s2 * (1.f / DDIM) - mu * mu;
        float rstd = rsqrtf(var + 1e-6f);

        float acc[16];
#pragma unroll
        for (int e = 0; e < 16; e++) acc[e] = 0.f;
#pragma unroll
        for (int j = 0; j < 8; j++) {
            float v = (xv[j] - mu) * rstd * nw[j] + nb[j];
            int d = j * 64 + lane;
            xnorm_bf[(size_t)row * DDIM + d] = f2bf(v);
            x_bf[(size_t)row * DDIM + d] = f2bf(xv[j]);
#pragma unroll
            for (int e = 0; e < 8; e++) {
                acc[e] += v * wgT[e * DDIM + d];
                acc[8 + e] += v * wnT[e * DDIM + d];
            }
        }
#pragma unroll
        for (int e = 0; e < 16; e++)
#pragma unroll
            for (int o = 32; o; o >>= 1) acc[e] += __shfl_xor(acc[e], o, 64);

        float cl[8], sd[8], nz[8];
#pragma unroll
        for (int e = 0; e < 8; e++) {
            cl[e] = acc[e];
            float t = acc[8 + e];
            float sp = fmaxf(t, 0.f) + log1pf(expf(-fabsf(t))); // stable softplus
            sd[e] = sp + 0.01f;
            nz[e] = cl[e] + noise[(size_t)row * NEXP + e] * sd[e];
        }
        // top-3 (strict > = lowest-index tie-break, matching lax.top_k)
        int idx[3]; float val[3]; u32 msk = 0;
#pragma unroll
        for (int t = 0; t < 3; t++) {
            float best = -INFINITY; int bi = 0;
#pragma unroll
            for (int e = 0; e < 8; e++)
                if (!((msk >> e) & 1) && nz[e] > best) { best = nz[e]; bi = e; }
            idx[t] = bi; val[t] = best; msk |= 1u << bi;
        }
        float e1 = expf(val[1] - val[0]);
        float g0 = 1.f / (1.f + e1), g1 = e1 / (1.f + e1);
        float thr_in = val[2], thr_out = val[1];

        if (lane == 0) {
            pair_expert[row * 2] = idx[0]; pair_gate[row * 2] = g0;
            pair_expert[row * 2 + 1] = idx[1]; pair_gate[row * 2 + 1] = g1;
            atomicAdd(&blk_g[idx[0]], g0); atomicAdd(&blk_g[idx[1]], g1);
            atomicAdd(&blk_c[idx[0]], 1); atomicAdd(&blk_c[idx[1]], 1);
#pragma unroll
            for (int e = 0; e < 8; e++) {
                float thr = (nz[e] > thr_in) ? thr_in : thr_out;
                float z = (cl[e] - thr) / sd[e];
                float p = 0.5f * (1.f + erff(z * 0.70710678118654752f));
                atomicAdd(&blk_l[e], p);
            }
        }
    }
    __syncthreads();
    if (tid < NEXP) {
        atomicAdd(smf + SM_GSUM + tid, blk_g[tid]);
        atomicAdd(smf + SM_LSUM + tid, blk_l[tid]);
        atomicAdd(&small[SM_CNT + tid], blk_c[tid]);
    }
}

// ---------------- scatter (+prefix +loss +load +rowpos inverse map) ----------------
__global__ __launch_bounds__(256) void scatter_kernel(
    const int* __restrict__ pair_expert, const float* __restrict__ pair_gate,
    int* __restrict__ small, int* __restrict__ bucket_rows, float* __restrict__ gate_by_pos,
    int* __restrict__ rowpos,
    float* __restrict__ out_loss, float* __restrict__ out_load)
{
    __shared__ int aoff[NEXP + 1];
    __shared__ int blk_cnt[NEXP];
    __shared__ int blk_base[NEXP];
    int tid = threadIdx.x;
    if (tid == 0) {
        int acc = 0; aoff[0] = 0;
        for (int e = 0; e < NEXP; e++) { acc += (small[SM_CNT + e] + 127) & ~127; aoff[e + 1] = acc; }
    }
    if (tid < NEXP) blk_cnt[tid] = 0;
    __syncthreads();
    int p = blockIdx.x * 256 + tid;
    int e = pair_expert[p];
    int local = atomicAdd(&blk_cnt[e], 1);
    __syncthreads();
    if (tid < NEXP)
        blk_base[tid] = aoff[tid] + atomicAdd(&small[SM_CUR + tid], blk_cnt[tid]);
    if (blockIdx.x == 0 && tid < NEXP + 1) small[SM_AOFF + tid] = aoff[tid];
    __syncthreads();
    int pos = blk_base[e] + local;
    bucket_rows[pos] = p >> 1;
    gate_by_pos[pos] = pair_gate[p];
    rowpos[p] = pos; // inverse map row-pair -> position (gemmC combine)

    if (blockIdx.x == 0 && tid == 0) {
        const float* gs = (const float*)small + SM_GSUM;
        const float* ls = (const float*)small + SM_LSUM;
        float cv[2];
        for (int t = 0; t < 2; t++) {
            const float* v = t ? ls : gs;
            float m = 0.f;
            for (int k = 0; k < NEXP; k++) m += v[k];
            m *= (1.f / NEXP);
            float var = 0.f;
            for (int k = 0; k < NEXP; k++) { float d = v[k] - m; var += d * d; }
            var *= (1.f / NEXP);
            cv[t] = var / (m * m + 1e-10f);
        }
        out_loss[0] = 0.01f * (cv[0] + cv[1]);
        int tot = 0;
        for (int k = 0; k < NEXP; k++) tot += small[SM_CNT + k];
        float inv = 1.f / (float)tot;
        for (int k = 0; k < NEXP; k++) out_load[k] = (float)small[SM_CNT + k] * inv;
    }
}

// ---------------- gemmA: mode0 only (R17: mode2 moved to gemmC) ----------------
// gathered x_norm @ W1[e]^T, +b1, SiLU -> a_buf bf16 (BK64 swizzled core).
// XCD-aware bijective block swizzle (T1): 1088 = 8 x 136; each XCD gets a
// contiguous run of x-tiles sharing one W1b N-panel.
__global__ __launch_bounds__(256) void gemmA_kernel(
    const u16* __restrict__ xnorm, const u16* __restrict__ W1b,
    const int* __restrict__ bucket_rows, const int* __restrict__ small,
    const float* __restrict__ b1, const u16* __restrict__ zeropage,
    u16* __restrict__ a_buf)
{
    constexpr int KD = 512;
    __shared__ __align__(16) u16 As[128 * 64];
    __shared__ __align__(16) u16 Bs[128 * 64];

    int tid = threadIdx.x;
    // XCD swizzle: d = dispatch index; w = work index; XCD(d)=d%8 gets w-chunk
    int d = blockIdx.y * 136 + blockIdx.x;
    int w = (d & 7) * 136 + (d >> 3);
    int base = (w % 136) * 128;
    int bn = (w / 136) * 128;
    if (base >= small[SM_AOFF + 8]) return;
    int e = 0;
    while (e < 7 && base >= small[SM_AOFF + e + 1]) ++e;
    const u16* Bsel = W1b + (size_t)e * HDIM * KD;

    int wave = tid >> 6, lane = tid & 63;
    int lr = lane >> 3;                 // row within 8-row chunk
    int lc = ((lane & 7) ^ lr) * 8;     // swizzled col-group (elements)

    const u16* ga[4]; const u16* gb[4];
    u16* la[4]; u16* lb[4];
#pragma unroll
    for (int c = 0; c < 4; c++) {
        int tr = wave * 32 + c * 8;     // chunk base row
        int r0 = bucket_rows[base + tr + lr];
        ga[c] = ((r0 < 0) ? zeropage : xnorm + (size_t)r0 * KD) + lc;
        gb[c] = Bsel + (size_t)(bn + tr + lr) * KD + lc;
        la[c] = &As[tr * 64];
        lb[c] = &Bs[tr * 64];
    }

    int wm = (wave & 1) * 64, wn = (wave >> 1) * 64;
    int fr = lane & 15, kq = lane >> 4, f7 = fr & 7;

    float4v acc[4][4];
#pragma unroll
    for (int i = 0; i < 4; i++)
#pragma unroll
        for (int j = 0; j < 4; j++) acc[i][j] = (float4v){0.f, 0.f, 0.f, 0.f};

    for (int k0 = 0; k0 < KD; k0 += 64) {
        __syncthreads();
#pragma unroll
        for (int c = 0; c < 4; c++) async_copy16(la[c], ga[c] + k0);
#pragma unroll
        for (int c = 0; c < 4; c++) async_copy16(lb[c], gb[c] + k0);
        __syncthreads();
        short8 af[4][2], bf[4][2];
#pragma unroll
        for (int mt = 0; mt < 4; mt++)
#pragma unroll
            for (int kh = 0; kh < 2; kh++)
                af[mt][kh] = *(const short8*)&As[(wm + mt * 16 + fr) * 64 + (((kq + 4 * kh) ^ f7) * 8)];
#pragma unroll
        for (int nt = 0; nt < 4; nt++)
#pragma unroll
            for (int kh = 0; kh < 2; kh++)
                bf[nt][kh] = *(const short8*)&Bs[(wn + nt * 16 + fr) * 64 + (((kq + 4 * kh) ^ f7) * 8)];
#pragma unroll
        for (int mt = 0; mt < 4; mt++)
#pragma unroll
            for (int nt = 0; nt < 4; nt++) {
                acc[mt][nt] = __builtin_amdgcn_mfma_f32_16x16x32_bf16(af[mt][0], bf[nt][0], acc[mt][nt], 0, 0, 0);
                acc[mt][nt] = __builtin_amdgcn_mfma_f32_16x16x32_bf16(af[mt][1], bf[nt][1], acc[mt][nt], 0, 0, 0);
            }
    }

    // epilogue: C/D layout col=lane&15, row=(lane>>4)*4+reg (m89-verified)
    int rbase = (lane >> 4) * 4, c16 = lane & 15;
#pragma unroll
    for (int nt = 0; nt < 4; nt++) {
        int gn = bn + wn + nt * 16 + c16;
        float bv = b1[e * HDIM + gn];
#pragma unroll
        for (int mt = 0; mt < 4; mt++) {
            int gm = base + wm + mt * 16 + rbase;
#pragma unroll
            for (int r = 0; r < 4; r++) {
                float h = acc[mt][nt][r] + bv;
                float a = h * __builtin_amdgcn_rcpf(1.f + __expf(-h)); // fast SiLU
                a_buf[(size_t)(gm + r) * HDIM + gn] = f2bf(a);
            }
        }
    }
}

// ---------------- gemmB: expert down-proj, DENSE PLAIN STORES ----------------
// 128x256 tile, 512 thr, BK32 2-buffer syncthreads core (R16-proven).
// ye[pos] = gate*(acc + b2[e]) — no atomics. + XCD swizzle (272 = 8 x 34).
__global__ __launch_bounds__(512) void gemmB_kernel(
    const u16* __restrict__ a_buf, const u16* __restrict__ W2b,
    const int* __restrict__ bucket_rows, const int* __restrict__ small,
    const float* __restrict__ b2, const float* __restrict__ gate_by_pos,
    float* __restrict__ ye)
{
    constexpr int KD = 1024;
    __shared__ __align__(16) u16 As[2][128 * 32];
    __shared__ __align__(16) u16 Bs[2][256 * 32];

    int tid = threadIdx.x;
    int wave = tid >> 6, lane = tid & 63;
    const int lrow = lane >> 2;                              // row within 16-row chunk
    const int kcol = (((lane & 3) ^ ((lane >> 3) & 3)) * 8); // pre-swizzled global col-group
    int wm = (wave >> 2) * 64, wn = (wave & 3) * 64;         // wave -> 64x64 of 128x256
    int fr = lane & 15, kq = lane >> 4;
    const int kg = ((kq ^ ((fr >> 1) & 3)) * 8);             // swizzled read group

    int d = blockIdx.y * 136 + blockIdx.x;
    int w = (d & 7) * 34 + (d >> 3);
    int base = (w % 136) * 128;
    int bn = (w / 136) * 256;
    if (base >= small[SM_AOFF + 8]) return;
    int e = 0;
    while (e < 7 && base >= small[SM_AOFF + e + 1]) ++e;

    const u16* ga0 = a_buf + (size_t)(base + wave * 16 + lrow) * KD + kcol;
    const u16* Bsel = W2b + (size_t)e * ODIM * KD;
    const u16* gb0 = Bsel + (size_t)(bn + wave * 32 + lrow) * KD + kcol;
    const u16* gb1 = Bsel + (size_t)(bn + wave * 32 + 16 + lrow) * KD + kcol;
    const int ofA = (wave * 16) * 32;
    const int ofB0 = (wave * 32) * 32;
    const int ofB1 = (wave * 32 + 16) * 32;

    float4v acc[4][4];
#pragma unroll
    for (int i = 0; i < 4; i++)
#pragma unroll
        for (int j = 0; j < 4; j++) acc[i][j] = (float4v){0.f, 0.f, 0.f, 0.f};

    constexpr int nk = KD >> 5; // 32
    async_copy16(&As[0][ofA], ga0);
    async_copy16(&Bs[0][ofB0], gb0);
    async_copy16(&Bs[0][ofB1], gb1);
    __syncthreads();

    int cur = 0;
    for (int t = 0; t < nk; ++t) {
        int nxt = cur ^ 1;
        if (t + 1 < nk) { // prefetch next tile; in flight across compute
            int k1 = (t + 1) << 5;
            async_copy16(&As[nxt][ofA], ga0 + k1);
            async_copy16(&Bs[nxt][ofB0], gb0 + k1);
            async_copy16(&Bs[nxt][ofB1], gb1 + k1);
        }
        short8 af[4], bf[4];
#pragma unroll
        for (int mt = 0; mt < 4; mt++) af[mt] = *(const short8*)&As[cur][(wm + mt * 16 + fr) * 32 + kg];
#pragma unroll
        for (int nt = 0; nt < 4; nt++) bf[nt] = *(const short8*)&Bs[cur][(wn + nt * 16 + fr) * 32 + kg];
#pragma unroll
        for (int mt = 0; mt < 4; mt++)
#pragma unroll
            for (int nt = 0; nt < 4; nt++)
                acc[mt][nt] = __builtin_amdgcn_mfma_f32_16x16x32_bf16(af[mt], bf[nt], acc[mt][nt], 0, 0, 0);
        __syncthreads();
        cur = nxt;
    }

    int rbase = (lane >> 4) * 4, c16 = lane & 15;
#pragma unroll
    for (int mt = 0; mt < 4; mt++) {
        int pos0 = base + wm + mt * 16 + rbase;
        int rows[4]; float gs[4];
#pragma unroll
        for (int r = 0; r < 4; r++) { rows[r] = bucket_rows[pos0 + r]; gs[r] = gate_by_pos[pos0 + r]; }
#pragma unroll
        for (int nt = 0; nt < 4; nt++) {
            int gn = bn + wn + nt * 16 + c16;
            float b2v = b2[e * ODIM + gn];
#pragma unroll
            for (int r = 0; r < 4; r++) {
                if (rows[r] >= 0)
                    ye[(size_t)(pos0 + r) * ODIM + gn] = gs[r] * (acc[mt][nt][r] + b2v);
            }
        }
    }
}

// ---------------- gemmC: mode2 + combine fused (R17) ----------------
// x_bf @ owT^T (128x128, BK32 2-buffer core) then epilogue reads ye[pos0/1]
// via rowpos and writes y ONCE: y = acc + ye0 + ye1. Deletes combine kernel
// and the mode2-y write + combine-y read round-trip (-33.5 MB).
// XCD swizzle: 256 = 8 x 32.
__global__ __launch_bounds__(256) void gemmC_kernel(
    const u16* __restrict__ xbf, const u16* __restrict__ owT,
    const int* __restrict__ rowpos, const float* __restrict__ ye,
    float* __restrict__ y)
{
    constexpr int KD = 512;
    __shared__ __align__(16) u16 As[2][128 * 32];
    __shared__ __align__(16) u16 Bs[2][128 * 32];

    int tid = threadIdx.x;
    int d = blockIdx.y * 64 + blockIdx.x;
    int w = (d & 7) * 32 + (d >> 3);
    int base = (w & 63) * 128;   // row tile (8192/128 = 64)
    int bn = (w >> 6) * 128;     // col tile (512/128 = 4)

    int wave = tid >> 6, lane = tid & 63;
    const int lrow = lane >> 2;
    const int kcol = (((lane & 3) ^ ((lane >> 3) & 3)) * 8);
    const int trow = wave * 32 + lrow;
    int wm = (wave & 1) * 64, wn = (wave >> 1) * 64;
    int fr = lane & 15, kq = lane >> 4;
    const int kg = ((kq ^ ((fr >> 1) & 3)) * 8);
    const u16* ga0 = xbf + (size_t)(base + trow) * KD + kcol;
    const u16* ga1 = xbf + (size_t)(base + trow + 16) * KD + kcol;
    const u16* gb0 = owT + (size_t)(bn + trow) * KD + kcol;
    const u16* gb1 = owT + (size_t)(bn + trow + 16) * KD + kcol;
    const int ofA0 = (wave * 32) * 32, ofA1 = (wave * 32 + 16) * 32;

    float4v acc[4][4];
#pragma unroll
    for (int i = 0; i < 4; i++)
#pragma unroll
        for (int j = 0; j < 4; j++) acc[i][j] = (float4v){0.f, 0.f, 0.f, 0.f};

    async_copy16(&As[0][ofA0], ga0); async_copy16(&As[0][ofA1], ga1);
    async_copy16(&Bs[0][ofA0], gb0); async_copy16(&Bs[0][ofA1], gb1);
    __syncthreads();
    int cur = 0;
    for (int t = 0; t < 16; ++t) {
        int nxt = cur ^ 1;
        if (t + 1 < 16) {
            int k1 = (t + 1) << 5;
            async_copy16(&As[nxt][ofA0], ga0 + k1);
            async_copy16(&As[nxt][ofA1], ga1 + k1);
            async_copy16(&Bs[nxt][ofA0], gb0 + k1);
            async_copy16(&Bs[nxt][ofA1], gb1 + k1);
        }
        short8 af[4], bf[4];
#pragma unroll
        for (int mt = 0; mt < 4; mt++) af[mt] = *(const short8*)&As[cur][(wm + mt * 16 + fr) * 32 + kg];
#pragma unroll
        for (int nt = 0; nt < 4; nt++) bf[nt] = *(const short8*)&Bs[cur][(wn + nt * 16 + fr) * 32 + kg];
#pragma unroll
        for (int mt = 0; mt < 4; mt++)
#pragma unroll
            for (int nt = 0; nt < 4; nt++)
                acc[mt][nt] = __builtin_amdgcn_mfma_f32_16x16x32_bf16(af[mt], bf[nt], acc[mt][nt], 0, 0, 0);
        __syncthreads();
        cur = nxt;
    }

    int rbase = (lane >> 4) * 4, c16 = lane & 15;
#pragma unroll
    for (int mt = 0; mt < 4; mt++) {
        int gm = base + wm + mt * 16 + rbase;
        int p0[4], p1[4];
#pragma unroll
        for (int r = 0; r < 4; r++) { p0[r] = rowpos[(gm + r) * 2]; p1[r] = rowpos[(gm + r) * 2 + 1]; }
#pragma unroll
        for (int nt = 0; nt < 4; nt++) {
            int gn = bn + wn + nt * 16 + c16;
#pragma unroll
            for (int r = 0; r < 4; r++)
                y[(size_t)(gm + r) * ODIM + gn] = acc[mt][nt][r]
                    + ye[(size_t)p0[r] * ODIM + gn] + ye[(size_t)p1[r] * ODIM + gn];
        }
    }
}

extern "C" void kernel_launch(void* const* d_in, const int* in_sizes, int n_in,
                              void* d_out, int out_size, void* d_ws, size_t ws_size,
                              hipStream_t stream)
{
    (void)in_sizes; (void)n_in; (void)out_size; (void)ws_size;
    const float* x = (const float*)d_in[0];
    // d_in[1] x_offsets, d_in[2] max_seq_len: unused by the reference math
    const float* noise = (const float*)d_in[3];
    const float* norm_w = (const float*)d_in[4];
    const float* norm_b = (const float*)d_in[5];
    const float* w_gate = (const float*)d_in[6];
    const float* w_noise = (const float*)d_in[7];
    const float* W1 = (const float*)d_in[8];
    const float* b1 = (const float*)d_in[9];
    const float* W2 = (const float*)d_in[10];
    const float* b2 = (const float*)d_in[11];
    const float* ow = (const float*)d_in[12];

    float* y = (float*)d_out;
    float* out_loss = y + (size_t)N_ROWS * ODIM;
    float* out_load = out_loss + 1;

    char* ws = (char*)d_ws;
    size_t off = 0;
    auto alloc = [&](size_t b) { size_t p = off; off = (off + b + 255) & ~(size_t)255; return p; };
    u16* xnorm_bf = (u16*)(ws + alloc((size_t)N_ROWS * DDIM * 2));
    u16* x_bf     = (u16*)(ws + alloc((size_t)N_ROWS * DDIM * 2));
    u16* W1b      = (u16*)(ws + alloc((size_t)NEXP * HDIM * DDIM * 2));
    u16* W2b      = (u16*)(ws + alloc((size_t)NEXP * ODIM * HDIM * 2));
    u16* owT      = (u16*)(ws + alloc((size_t)DDIM * ODIM * 2));
    u16* a_buf    = (u16*)(ws + alloc((size_t)MAXPOS * HDIM * 2));
    float* ye     = (float*)(ws + alloc((size_t)MAXPOS * ODIM * 4));
    int* pair_expert = (int*)(ws + alloc((size_t)MAXPAIRS * 4));
    float* pair_gate = (float*)(ws + alloc((size_t)MAXPAIRS * 4));
    float* gate_by_pos = (float*)(ws + alloc((size_t)MAXPOS * 4));
    int* bucket_rows = (int*)(ws + alloc((size_t)MAXPOS * 4));
    int* rowpos      = (int*)(ws + alloc((size_t)MAXPAIRS * 4));
    int* small       = (int*)(ws + alloc(SM_WORDS * 4));
    float* zeropage  = (float*)(ws + alloc(2048));

    init1_kernel<<<1, 512, 0, stream>>>(small, zeropage);
    combo_kernel<<<GATE_BLOCKS + W1CONV_BLOCKS + OWT_BLOCKS + BUCKET_BLOCKS + W2CONV_BLOCKS,
                   256, 0, stream>>>(
        x, noise, norm_w, norm_b, w_gate, w_noise, W1, ow, W2,
        xnorm_bf, x_bf, pair_expert, pair_gate, W1b, owT, W2b, small, bucket_rows);
    scatter_kernel<<<MAXPAIRS / 256, 256, 0, stream>>>(pair_expert, pair_gate, small,
                                                       bucket_rows, gate_by_pos, rowpos,
                                                       out_loss, out_load);
    gemmA_kernel<<<dim3(MAXTILES, 8), 256, 0, stream>>>(xnorm_bf, W1b, bucket_rows, small, b1,
                                                        (const u16*)zeropage, a_buf);
    gemmB_kernel<<<dim3(MAXTILES, 2), 512, 0, stream>>>(a_buf, W2b, bucket_rows,
                                                        small, b2, gate_by_pos, ye);
    gemmC_kernel<<<dim3(64, 4), 256, 0, stream>>>(x_bf, owT, rowpos, ye, y);
}

// Round 9
// 249.503 us; speedup vs baseline: 1.0495x; 1.0495x over previous
//
#include <hip/hip_runtime.h>
#include <math.h>

typedef unsigned short u16;
typedef unsigned int u32;

#define N_ROWS 8192
#define DDIM 512
#define HDIM 1024
#define ODIM 512
#define NEXP 8
#define MAXPAIRS (N_ROWS * 2)          // 16384
#define MAXPOS (MAXPAIRS + NEXP * 128) // 17408 (per-expert segments 128-aligned)
#define MAXTILES (MAXPOS / 128)        // 136

// small-region word indices (in d_ws)
#define SM_CNT 0   // 8 ints: expert lengths
#define SM_CUR 8   // 8 ints: scatter cursors
#define SM_AOFF 16 // 9 ints: aligned bucket offsets
#define SM_GSUM 32 // 8 floats: sum of gates per expert
#define SM_LSUM 40 // 8 floats: sum of load_probs per expert
#define SM_WORDS 64

using short8 = __attribute__((ext_vector_type(8))) short;
using float4v = __attribute__((ext_vector_type(4))) float;

__device__ __forceinline__ u16 f2bf(float f) {
    union { float f; u32 u; } v; v.f = f;
    u32 u = v.u;
    return (u16)((u + 0x7fffu + ((u >> 16) & 1u)) >> 16);
}

// async global->LDS, 16B per lane; HW places lane i at lds_base + i*16
__device__ __forceinline__ void async_copy16(u16* lds, const u16* g) {
    __builtin_amdgcn_global_load_lds(
        (const __attribute__((address_space(1))) void*)g,
        (__attribute__((address_space(3))) void*)lds, 16, 0, 0);
}

// ---------------- init1: zero small + zeropage ----------------
__global__ __launch_bounds__(512) void init1_kernel(int* small, float* zeropage) {
    int i = threadIdx.x;
    if (i < SM_WORDS) small[i] = 0;
    zeropage[i] = 0.f; // 512 floats
}

// ---------------- prep: W1 convert + ow transpose + bucket init + W2 convert ----------------
// R18: split from combo — these streaming blocks no longer inherit the gating
// body's 33KB LDS (was capping them at 4 blocks/CU and exposing load latency).
#define W1CONV_BLOCKS 4096 // (8*1024*512/4) / 256
#define OWT_BLOCKS 256
#define BUCKET_BLOCKS 68
#define W2CONV_BLOCKS 2048 // (8*512*1024/4) float4s / 512 per block
__global__ __launch_bounds__(256) void prep_kernel(
    const float* __restrict__ W1, const float* __restrict__ ow,
    const float* __restrict__ W2,
    u16* __restrict__ W1b, u16* __restrict__ owT, u16* __restrict__ W2b,
    int* __restrict__ bucket_rows)
{
    __shared__ __align__(16) float tile[32][33];
    int cb = blockIdx.x, tid = threadIdx.x;
    if (cb < W1CONV_BLOCKS) {
        size_t i = (size_t)cb * 256 + tid;
        float4 v = ((const float4*)W1)[i];
        ushort4 o;
        o.x = f2bf(v.x); o.y = f2bf(v.y); o.z = f2bf(v.z); o.w = f2bf(v.w);
        ((ushort4*)W1b)[i] = o;
    } else if (cb < W1CONV_BLOCKS + OWT_BLOCKS) {
        int t = cb - W1CONV_BLOCKS;
        int bx = (t & 15) * 32, by = (t >> 4) * 32;
        int tx = tid & 31, ty = tid >> 5; // 32 x 8
        for (int r = ty; r < 32; r += 8) tile[r][tx] = ow[(size_t)(by + r) * ODIM + bx + tx];
        __syncthreads();
        for (int r = ty; r < 32; r += 8) owT[(size_t)(bx + r) * DDIM + by + tx] = f2bf(tile[tx][r]);
    } else if (cb < W1CONV_BLOCKS + OWT_BLOCKS + BUCKET_BLOCKS) {
        int i = (cb - W1CONV_BLOCKS - OWT_BLOCKS) * 256 + tid;
        if (i < MAXPOS) bucket_rows[i] = -1;
    } else { // W2 convert: 2048 blocks x 512 float4s
        int j = cb - W1CONV_BLOCKS - OWT_BLOCKS - BUCKET_BLOCKS;
        size_t i = (size_t)j * 512 + tid;
#pragma unroll
        for (int t = 0; t < 2; t++, i += 256) {
            float4 v = ((const float4*)W2)[i];
            ushort4 o;
            o.x = f2bf(v.x); o.y = f2bf(v.y); o.z = f2bf(v.z); o.w = f2bf(v.w);
            ((ushort4*)W2b)[i] = o;
        }
    }
}

// ---------------- gate: layernorm + gating (R18 rewrite) ----------------
// Per block: 16 rows. fp32 math identical to the reference path (no MFMA —
// bf16 gating would risk top-k flips). Changes vs old combo gating:
//  (a) value-split butterfly: 16-value all-reduce in ~64 ops (was 192),
//      result distributed (lane 4e+j holds sum e) -> parked in LDS.
//  (b) softplus/top-k/erf tail runs lane-parallel (16 lanes x 16 rows per
//      block) instead of lane0-serial (was 1/64 lanes, 4 rows serial/wave).
#define GATE_BLOCKS 512 // N_ROWS/16
__global__ __launch_bounds__(256) void gate_kernel(
    const float* __restrict__ x, const float* __restrict__ noise,
    const float* __restrict__ norm_w, const float* __restrict__ norm_b,
    const float* __restrict__ w_gate, const float* __restrict__ w_noise,
    u16* __restrict__ xnorm_bf, u16* __restrict__ x_bf,
    int* __restrict__ pair_expert, float* __restrict__ pair_gate,
    int* __restrict__ small)
{
    __shared__ __align__(16) float sh[2 * NEXP * DDIM + 16 * 17 + 32];
    float* wgT = sh;                    // [e][d] transposed
    float* wnT = sh + NEXP * DDIM;
    float* lg = sh + 2 * NEXP * DDIM;   // [16][17]: cols 0..7 clean, 8..15 noise-acc
    float* blk_g = lg + 16 * 17;
    float* blk_l = blk_g + NEXP;
    int* blk_c = (int*)(blk_l + NEXP);
    float* smf = (float*)small;

    int b = blockIdx.x, tid = threadIdx.x;
    for (int i = tid; i < NEXP * DDIM; i += 256) {
        int d = i >> 3, e = i & 7;
        wgT[e * DDIM + d] = w_gate[i];
        wnT[e * DDIM + d] = w_noise[i];
    }
    if (tid < NEXP) { blk_g[tid] = 0.f; blk_l[tid] = 0.f; blk_c[tid] = 0; }
    __syncthreads();

    int wave = tid >> 6, lane = tid & 63;
    float nw[8], nb[8];
#pragma unroll
    for (int j = 0; j < 8; j++) { nw[j] = norm_w[j * 64 + lane]; nb[j] = norm_b[j * 64 + lane]; }

    bool l5 = (lane & 32) != 0, l4 = (lane & 16) != 0;
    bool l3 = (lane & 8) != 0, l2 = (lane & 4) != 0;

    for (int r = 0; r < 4; ++r) {
        int lrow16 = wave * 4 + r;
        int row = b * 16 + lrow16;
        const float* xr = x + (size_t)row * DDIM;
        float xv[8], s = 0.f, s2 = 0.f;
#pragma unroll
        for (int j = 0; j < 8; j++) { float v = xr[j * 64 + lane]; xv[j] = v; s += v; s2 += v * v; }
#pragma unroll
        for (int o = 32; o; o >>= 1) { s += __shfl_xor(s, o, 64); s2 += __shfl_xor(s2, o, 64); }
        float mu = s * (1.f / DDIM);
        float var = s2 * (1.f / DDIM) - mu * mu;
        float rstd = rsqrtf(var + 1e-6f);

        float acc[16];
#pragma unroll
        for (int e = 0; e < 16; e++) acc[e] = 0.f;
#pragma unroll
        for (int j = 0; j < 8; j++) {
            float v = (xv[j] - mu) * rstd * nw[j] + nb[j];
            int d = j * 64 + lane;
            xnorm_bf[(size_t)row * DDIM + d] = f2bf(v);
            x_bf[(size_t)row * DDIM + d] = f2bf(xv[j]);
#pragma unroll
            for (int e = 0; e < 8; e++) {
                acc[e] += v * wgT[e * DDIM + d];
                acc[8 + e] += v * wnT[e * DDIM + d];
            }
        }
        // value-split butterfly: lane l ends holding full sum of value (l>>2)&15
        float t8[8];
#pragma unroll
        for (int v = 0; v < 8; v++) {
            float snd = l5 ? acc[v] : acc[v + 8];
            float kp = l5 ? acc[v + 8] : acc[v];
            t8[v] = kp + __shfl_xor(snd, 32, 64);
        }
        float t4[4];
#pragma unroll
        for (int v = 0; v < 4; v++) {
            float snd = l4 ? t8[v] : t8[v + 4];
            float kp = l4 ? t8[v + 4] : t8[v];
            t4[v] = kp + __shfl_xor(snd, 16, 64);
        }
        float t2[2];
#pragma unroll
        for (int v = 0; v < 2; v++) {
            float snd = l3 ? t4[v] : t4[v + 2];
            float kp = l3 ? t4[v + 2] : t4[v];
            t2[v] = kp + __shfl_xor(snd, 8, 64);
        }
        {
            float snd = l2 ? t2[0] : t2[1];
            float kp = l2 ? t2[1] : t2[0];
            float t1 = kp + __shfl_xor(snd, 4, 64);
            t1 += __shfl_xor(t1, 2, 64);
            t1 += __shfl_xor(t1, 1, 64);
            if ((lane & 3) == 0) lg[lrow16 * 17 + ((lane >> 2) & 15)] = t1;
        }
    }
    __syncthreads();

    if (tid < 16) { // one lane per row: softplus + noisy + top3 + erf + LDS atomics
        int row = b * 16 + tid;
        float cl[8], sd[8], nz[8];
#pragma unroll
        for (int e = 0; e < 8; e++) {
            cl[e] = lg[tid * 17 + e];
            float t = lg[tid * 17 + 8 + e];
            float sp = fmaxf(t, 0.f) + log1pf(expf(-fabsf(t))); // stable softplus
            sd[e] = sp + 0.01f;
            nz[e] = cl[e] + noise[(size_t)row * NEXP + e] * sd[e];
        }
        // top-3 (strict > = lowest-index tie-break, matching lax.top_k)
        int idx[3]; float val[3]; u32 msk = 0;
#pragma unroll
        for (int t = 0; t < 3; t++) {
            float best = -INFINITY; int bi = 0;
#pragma unroll
            for (int e = 0; e < 8; e++)
                if (!((msk >> e) & 1) && nz[e] > best) { best = nz[e]; bi = e; }
            idx[t] = bi; val[t] = best; msk |= 1u << bi;
        }
        float e1 = expf(val[1] - val[0]);
        float g0 = 1.f / (1.f + e1), g1 = e1 / (1.f + e1);
        float thr_in = val[2], thr_out = val[1];

        pair_expert[row * 2] = idx[0]; pair_gate[row * 2] = g0;
        pair_expert[row * 2 + 1] = idx[1]; pair_gate[row * 2 + 1] = g1;
        atomicAdd(&blk_g[idx[0]], g0); atomicAdd(&blk_g[idx[1]], g1);
        atomicAdd(&blk_c[idx[0]], 1); atomicAdd(&blk_c[idx[1]], 1);
#pragma unroll
        for (int e = 0; e < 8; e++) {
            float thr = (nz[e] > thr_in) ? thr_in : thr_out;
            float z = (cl[e] - thr) / sd[e];
            float p = 0.5f * (1.f + erff(z * 0.70710678118654752f));
            atomicAdd(&blk_l[e], p);
        }
    }
    __syncthreads();
    if (tid < NEXP) {
        atomicAdd(smf + SM_GSUM + tid, blk_g[tid]);
        atomicAdd(smf + SM_LSUM + tid, blk_l[tid]);
        atomicAdd(&small[SM_CNT + tid], blk_c[tid]);
    }
}

// ---------------- scatter (+prefix +loss +load +rowpos inverse map) ----------------
__global__ __launch_bounds__(256) void scatter_kernel(
    const int* __restrict__ pair_expert, const float* __restrict__ pair_gate,
    int* __restrict__ small, int* __restrict__ bucket_rows, float* __restrict__ gate_by_pos,
    int* __restrict__ rowpos,
    float* __restrict__ out_loss, float* __restrict__ out_load)
{
    __shared__ int aoff[NEXP + 1];
    __shared__ int blk_cnt[NEXP];
    __shared__ int blk_base[NEXP];
    int tid = threadIdx.x;
    if (tid == 0) {
        int acc = 0; aoff[0] = 0;
        for (int e = 0; e < NEXP; e++) { acc += (small[SM_CNT + e] + 127) & ~127; aoff[e + 1] = acc; }
    }
    if (tid < NEXP) blk_cnt[tid] = 0;
    __syncthreads();
    int p = blockIdx.x * 256 + tid;
    int e = pair_expert[p];
    int local = atomicAdd(&blk_cnt[e], 1);
    __syncthreads();
    if (tid < NEXP)
        blk_base[tid] = aoff[tid] + atomicAdd(&small[SM_CUR + tid], blk_cnt[tid]);
    if (blockIdx.x == 0 && tid < NEXP + 1) small[SM_AOFF + tid] = aoff[tid];
    __syncthreads();
    int pos = blk_base[e] + local;
    bucket_rows[pos] = p >> 1;
    gate_by_pos[pos] = pair_gate[p];
    rowpos[p] = pos; // inverse map row-pair -> position (combine)

    if (blockIdx.x == 0 && tid == 0) {
        const float* gs = (const float*)small + SM_GSUM;
        const float* ls = (const float*)small + SM_LSUM;
        float cv[2];
        for (int t = 0; t < 2; t++) {
            const float* v = t ? ls : gs;
            float m = 0.f;
            for (int k = 0; k < NEXP; k++) m += v[k];
            m *= (1.f / NEXP);
            float var = 0.f;
            for (int k = 0; k < NEXP; k++) { float d = v[k] - m; var += d * d; }
            var *= (1.f / NEXP);
            cv[t] = var / (m * m + 1e-10f);
        }
        out_loss[0] = 0.01f * (cv[0] + cv[1]);
        int tot = 0;
        for (int k = 0; k < NEXP; k++) tot += small[SM_CNT + k];
        float inv = 1.f / (float)tot;
        for (int k = 0; k < NEXP; k++) out_load[k] = (float)small[SM_CNT + k] * inv;
    }
}

// ---------------- gemmA: mode0 + mode2 (R7-proven structure, no swizzle) ----------------
// y<8:  gathered x_norm @ W1[e]^T, +b1, SiLU -> a_buf bf16 (BK64 swizzled core)
// y 8,9: mode2 x_bf @ owT^T -> PLAIN STORES to y (combine adds expert terms).
__global__ __launch_bounds__(256) void gemmA_kernel(
    const u16* __restrict__ xnorm, const u16* __restrict__ W1b,
    const u16* __restrict__ xbf, const u16* __restrict__ owT,
    const int* __restrict__ bucket_rows, const int* __restrict__ small,
    const float* __restrict__ b1, const u16* __restrict__ zeropage,
    u16* __restrict__ a_buf, float* __restrict__ y)
{
    constexpr int KD = 512;
    __shared__ __align__(16) u16 As[128 * 64];
    __shared__ __align__(16) u16 Bs[128 * 64];

    int tid = threadIdx.x;
    if (blockIdx.y >= 8) { // ---- mode2: x_bf @ owT^T, 128x128, BK32 2-buffer, plain stores ----
        int j = (blockIdx.y - 8) * 136 + blockIdx.x;
        if (j >= 256) return;
        int base = (j >> 2) * 128, bn = (j & 3) * 128;
        int wave = tid >> 6, lane = tid & 63;
        const int lrow = lane >> 2;
        const int kcol = (((lane & 3) ^ ((lane >> 3) & 3)) * 8);
        const int trow = wave * 32 + lrow;
        int wm = (wave & 1) * 64, wn = (wave >> 1) * 64;
        int fr = lane & 15, kq = lane >> 4;
        const int kg = ((kq ^ ((fr >> 1) & 3)) * 8);
        const u16* ga0 = xbf + (size_t)(base + trow) * KD + kcol;
        const u16* ga1 = xbf + (size_t)(base + trow + 16) * KD + kcol;
        const u16* gb0 = owT + (size_t)(bn + trow) * KD + kcol;
        const u16* gb1 = owT + (size_t)(bn + trow + 16) * KD + kcol;
        u16* As2 = (u16*)As; u16* Bs2 = (u16*)Bs; // reused as [2][128*32]
        const int ofA0 = (wave * 32) * 32, ofA1 = (wave * 32 + 16) * 32;

        float4v acc[4][4];
#pragma unroll
        for (int i = 0; i < 4; i++)
#pragma unroll
            for (int jj = 0; jj < 4; jj++) acc[i][jj] = (float4v){0.f, 0.f, 0.f, 0.f};

        async_copy16(As2 + ofA0, ga0); async_copy16(As2 + ofA1, ga1);
        async_copy16(Bs2 + ofA0, gb0); async_copy16(Bs2 + ofA1, gb1);
        __syncthreads();
        int cur = 0;
        for (int t = 0; t < 16; ++t) {
            int nxt = cur ^ 1;
            if (t + 1 < 16) {
                int k1 = (t + 1) << 5;
                async_copy16(As2 + nxt * 4096 + ofA0, ga0 + k1);
                async_copy16(As2 + nxt * 4096 + ofA1, ga1 + k1);
                async_copy16(Bs2 + nxt * 4096 + ofA0, gb0 + k1);
                async_copy16(Bs2 + nxt * 4096 + ofA1, gb1 + k1);
            }
            short8 af[4], bf[4];
#pragma unroll
            for (int mt = 0; mt < 4; mt++) af[mt] = *(const short8*)&As2[cur * 4096 + (wm + mt * 16 + fr) * 32 + kg];
#pragma unroll
            for (int nt = 0; nt < 4; nt++) bf[nt] = *(const short8*)&Bs2[cur * 4096 + (wn + nt * 16 + fr) * 32 + kg];
#pragma unroll
            for (int mt = 0; mt < 4; mt++)
#pragma unroll
                for (int nt = 0; nt < 4; nt++)
                    acc[mt][nt] = __builtin_amdgcn_mfma_f32_16x16x32_bf16(af[mt], bf[nt], acc[mt][nt], 0, 0, 0);
            __syncthreads();
            cur = nxt;
        }
        int rbase = (lane >> 4) * 4, c16 = lane & 15;
#pragma unroll
        for (int mt = 0; mt < 4; mt++) {
            int gm = base + wm + mt * 16 + rbase;
#pragma unroll
            for (int nt = 0; nt < 4; nt++) {
                int gn = bn + wn + nt * 16 + c16;
#pragma unroll
                for (int r = 0; r < 4; r++)
                    y[(size_t)(gm + r) * ODIM + gn] = acc[mt][nt][r];
            }
        }
        return;
    }

    // ---- mode0: BK64 swizzled 128x128 (R5 proven core) ----
    int base = blockIdx.x * 128;
    if (base >= small[SM_AOFF + 8]) return;
    int e = 0;
    while (e < 7 && base >= small[SM_AOFF + e + 1]) ++e;
    int bn = blockIdx.y * 128;
    const u16* Bsel = W1b + (size_t)e * HDIM * KD;

    int wave = tid >> 6, lane = tid & 63;
    int lr = lane >> 3;                 // row within 8-row chunk
    int lc = ((lane & 7) ^ lr) * 8;     // swizzled col-group (elements)

    const u16* ga[4]; const u16* gb[4];
    u16* la[4]; u16* lb[4];
#pragma unroll
    for (int c = 0; c < 4; c++) {
        int tr = wave * 32 + c * 8;     // chunk base row
        int r0 = bucket_rows[base + tr + lr];
        ga[c] = ((r0 < 0) ? zeropage : xnorm + (size_t)r0 * KD) + lc;
        gb[c] = Bsel + (size_t)(bn + tr + lr) * KD + lc;
        la[c] = &As[tr * 64];
        lb[c] = &Bs[tr * 64];
    }

    int wm = (wave & 1) * 64, wn = (wave >> 1) * 64;
    int fr = lane & 15, kq = lane >> 4, f7 = fr & 7;

    float4v acc[4][4];
#pragma unroll
    for (int i = 0; i < 4; i++)
#pragma unroll
        for (int j = 0; j < 4; j++) acc[i][j] = (float4v){0.f, 0.f, 0.f, 0.f};

    for (int k0 = 0; k0 < KD; k0 += 64) {
        __syncthreads();
#pragma unroll
        for (int c = 0; c < 4; c++) async_copy16(la[c], ga[c] + k0);
#pragma unroll
        for (int c = 0; c < 4; c++) async_copy16(lb[c], gb[c] + k0);
        __syncthreads();
        short8 af[4][2], bf[4][2];
#pragma unroll
        for (int mt = 0; mt < 4; mt++)
#pragma unroll
            for (int kh = 0; kh < 2; kh++)
                af[mt][kh] = *(const short8*)&As[(wm + mt * 16 + fr) * 64 + (((kq + 4 * kh) ^ f7) * 8)];
#pragma unroll
        for (int nt = 0; nt < 4; nt++)
#pragma unroll
            for (int kh = 0; kh < 2; kh++)
                bf[nt][kh] = *(const short8*)&Bs[(wn + nt * 16 + fr) * 64 + (((kq + 4 * kh) ^ f7) * 8)];
#pragma unroll
        for (int mt = 0; mt < 4; mt++)
#pragma unroll
            for (int nt = 0; nt < 4; nt++) {
                acc[mt][nt] = __builtin_amdgcn_mfma_f32_16x16x32_bf16(af[mt][0], bf[nt][0], acc[mt][nt], 0, 0, 0);
                acc[mt][nt] = __builtin_amdgcn_mfma_f32_16x16x32_bf16(af[mt][1], bf[nt][1], acc[mt][nt], 0, 0, 0);
            }
    }

    // epilogue: C/D layout col=lane&15, row=(lane>>4)*4+reg (m89-verified)
    int rbase = (lane >> 4) * 4, c16 = lane & 15;
#pragma unroll
    for (int nt = 0; nt < 4; nt++) {
        int gn = bn + wn + nt * 16 + c16;
        float bv = b1[e * HDIM + gn];
#pragma unroll
        for (int mt = 0; mt < 4; mt++) {
            int gm = base + wm + mt * 16 + rbase;
#pragma unroll
            for (int r = 0; r < 4; r++) {
                float h = acc[mt][nt][r] + bv;
                float a = h * __builtin_amdgcn_rcpf(1.f + __expf(-h)); // fast SiLU
                a_buf[(size_t)(gm + r) * HDIM + gn] = f2bf(a);
            }
        }
    }
}

// ---------------- gemmB: expert down-proj, DENSE PLAIN STORES (R16-proven) ----------------
// 128x256 tile, 512 thr, BK32 2-buffer syncthreads core, no atomics.
__global__ __launch_bounds__(512) void gemmB_kernel(
    const u16* __restrict__ a_buf, const u16* __restrict__ W2b,
    const int* __restrict__ bucket_rows, const int* __restrict__ small,
    const float* __restrict__ b2, const float* __restrict__ gate_by_pos,
    float* __restrict__ ye)
{
    constexpr int KD = 1024;
    __shared__ __align__(16) u16 As[2][128 * 32];
    __shared__ __align__(16) u16 Bs[2][256 * 32];

    int tid = threadIdx.x;
    int wave = tid >> 6, lane = tid & 63;
    const int lrow = lane >> 2;                              // row within 16-row chunk
    const int kcol = (((lane & 3) ^ ((lane >> 3) & 3)) * 8); // pre-swizzled global col-group
    int wm = (wave >> 2) * 64, wn = (wave & 3) * 64;         // wave -> 64x64 of 128x256
    int fr = lane & 15, kq = lane >> 4;
    const int kg = ((kq ^ ((fr >> 1) & 3)) * 8);             // swizzled read group

    int base = blockIdx.x * 128;
    if (base >= small[SM_AOFF + 8]) return;
    int e = 0;
    while (e < 7 && base >= small[SM_AOFF + e + 1]) ++e;
    int bn = blockIdx.y * 256;

    const u16* ga0 = a_buf + (size_t)(base + wave * 16 + lrow) * KD + kcol;
    const u16* Bsel = W2b + (size_t)e * ODIM * KD;
    const u16* gb0 = Bsel + (size_t)(bn + wave * 32 + lrow) * KD + kcol;
    const u16* gb1 = Bsel + (size_t)(bn + wave * 32 + 16 + lrow) * KD + kcol;
    const int ofA = (wave * 16) * 32;
    const int ofB0 = (wave * 32) * 32;
    const int ofB1 = (wave * 32 + 16) * 32;

    float4v acc[4][4];
#pragma unroll
    for (int i = 0; i < 4; i++)
#pragma unroll
        for (int j = 0; j < 4; j++) acc[i][j] = (float4v){0.f, 0.f, 0.f, 0.f};

    constexpr int nk = KD >> 5; // 32
    async_copy16(&As[0][ofA], ga0);
    async_copy16(&Bs[0][ofB0], gb0);
    async_copy16(&Bs[0][ofB1], gb1);
    __syncthreads();

    int cur = 0;
    for (int t = 0; t < nk; ++t) {
        int nxt = cur ^ 1;
        if (t + 1 < nk) { // prefetch next tile; in flight across compute
            int k1 = (t + 1) << 5;
            async_copy16(&As[nxt][ofA], ga0 + k1);
            async_copy16(&Bs[nxt][ofB0], gb0 + k1);
            async_copy16(&Bs[nxt][ofB1], gb1 + k1);
        }
        short8 af[4], bf[4];
#pragma unroll
        for (int mt = 0; mt < 4; mt++) af[mt] = *(const short8*)&As[cur][(wm + mt * 16 + fr) * 32 + kg];
#pragma unroll
        for (int nt = 0; nt < 4; nt++) bf[nt] = *(const short8*)&Bs[cur][(wn + nt * 16 + fr) * 32 + kg];
#pragma unroll
        for (int mt = 0; mt < 4; mt++)
#pragma unroll
            for (int nt = 0; nt < 4; nt++)
                acc[mt][nt] = __builtin_amdgcn_mfma_f32_16x16x32_bf16(af[mt], bf[nt], acc[mt][nt], 0, 0, 0);
        __syncthreads();
        cur = nxt;
    }

    int rbase = (lane >> 4) * 4, c16 = lane & 15;
#pragma unroll
    for (int mt = 0; mt < 4; mt++) {
        int pos0 = base + wm + mt * 16 + rbase;
        int rows[4]; float gs[4];
#pragma unroll
        for (int r = 0; r < 4; r++) { rows[r] = bucket_rows[pos0 + r]; gs[r] = gate_by_pos[pos0 + r]; }
#pragma unroll
        for (int nt = 0; nt < 4; nt++) {
            int gn = bn + wn + nt * 16 + c16;
            float b2v = b2[e * ODIM + gn];
#pragma unroll
            for (int r = 0; r < 4; r++) {
                if (rows[r] >= 0)
                    ye[(size_t)(pos0 + r) * ODIM + gn] = gs[r] * (acc[mt][nt][r] + b2v);
            }
        }
    }
}

// ---------------- combine: y[row] = y_mode2[row] + ye[pos0] + ye[pos1] ----------------
__global__ __launch_bounds__(256) void combine_kernel(
    const float* __restrict__ ye, const int* __restrict__ rowpos,
    float* __restrict__ y)
{
    int tid = threadIdx.x;
    int row = blockIdx.x * 16 + (tid >> 4);
    int c0 = (tid & 15) * 32;
    int p0 = rowpos[row * 2];
    int p1 = rowpos[row * 2 + 1];
    const float4* e0 = (const float4*)(ye + (size_t)p0 * ODIM + c0);
    const float4* e1 = (const float4*)(ye + (size_t)p1 * ODIM + c0);
    float4* yp = (float4*)(y + (size_t)row * ODIM + c0);
#pragma unroll
    for (int i = 0; i < 8; i++) {
        float4 a = yp[i], b = e0[i], c = e1[i];
        a.x += b.x + c.x; a.y += b.y + c.y; a.z += b.z + c.z; a.w += b.w + c.w;
        yp[i] = a;
    }
}

extern "C" void kernel_launch(void* const* d_in, const int* in_sizes, int n_in,
                              void* d_out, int out_size, void* d_ws, size_t ws_size,
                              hipStream_t stream)
{
    (void)in_sizes; (void)n_in; (void)out_size; (void)ws_size;
    const float* x = (const float*)d_in[0];
    // d_in[1] x_offsets, d_in[2] max_seq_len: unused by the reference math
    const float* noise = (const float*)d_in[3];
    const float* norm_w = (const float*)d_in[4];
    const float* norm_b = (const float*)d_in[5];
    const float* w_gate = (const float*)d_in[6];
    const float* w_noise = (const float*)d_in[7];
    const float* W1 = (const float*)d_in[8];
    const float* b1 = (const float*)d_in[9];
    const float* W2 = (const float*)d_in[10];
    const float* b2 = (const float*)d_in[11];
    const float* ow = (const float*)d_in[12];

    float* y = (float*)d_out;
    float* out_loss = y + (size_t)N_ROWS * ODIM;
    float* out_load = out_loss + 1;

    char* ws = (char*)d_ws;
    size_t off = 0;
    auto alloc = [&](size_t b) { size_t p = off; off = (off + b + 255) & ~(size_t)255; return p; };
    u16* xnorm_bf = (u16*)(ws + alloc((size_t)N_ROWS * DDIM * 2));
    u16* x_bf     = (u16*)(ws + alloc((size_t)N_ROWS * DDIM * 2));
    u16* W1b      = (u16*)(ws + alloc((size_t)NEXP * HDIM * DDIM * 2));
    u16* W2b      = (u16*)(ws + alloc((size_t)NEXP * ODIM * HDIM * 2));
    u16* owT      = (u16*)(ws + alloc((size_t)DDIM * ODIM * 2));
    u16* a_buf    = (u16*)(ws + alloc((size_t)MAXPOS * HDIM * 2));
    float* ye     = (float*)(ws + alloc((size_t)MAXPOS * ODIM * 4));
    int* pair_expert = (int*)(ws + alloc((size_t)MAXPAIRS * 4));
    float* pair_gate = (float*)(ws + alloc((size_t)MAXPAIRS * 4));
    float* gate_by_pos = (float*)(ws + alloc((size_t)MAXPOS * 4));
    int* bucket_rows = (int*)(ws + alloc((size_t)MAXPOS * 4));
    int* rowpos      = (int*)(ws + alloc((size_t)MAXPAIRS * 4));
    int* small       = (int*)(ws + alloc(SM_WORDS * 4));
    float* zeropage  = (float*)(ws + alloc(2048));

    init1_kernel<<<1, 512, 0, stream>>>(small, zeropage);
    prep_kernel<<<W1CONV_BLOCKS + OWT_BLOCKS + BUCKET_BLOCKS + W2CONV_BLOCKS, 256, 0, stream>>>(
        W1, ow, W2, W1b, owT, W2b, bucket_rows);
    gate_kernel<<<GATE_BLOCKS, 256, 0, stream>>>(
        x, noise, norm_w, norm_b, w_gate, w_noise,
        xnorm_bf, x_bf, pair_expert, pair_gate, small);
    scatter_kernel<<<MAXPAIRS / 256, 256, 0, stream>>>(pair_expert, pair_gate, small,
                                                       bucket_rows, gate_by_pos, rowpos,
                                                       out_loss, out_load);
    gemmA_kernel<<<dim3(MAXTILES, 8 + 2), 256, 0, stream>>>(xnorm_bf, W1b,
                                                            x_bf, owT, bucket_rows, small, b1,
                                                            (const u16*)zeropage, a_buf, y);
    gemmB_kernel<<<dim3(MAXTILES, 2), 512, 0, stream>>>(a_buf, W2b, bucket_rows,
                                                        small, b2, gate_by_pos, ye);
    combine_kernel<<<N_ROWS / 16, 256, 0, stream>>>(ye, rowpos, y);
}

// Round 10
// 237.919 us; speedup vs baseline: 1.1006x; 1.0487x over previous
//
#include <hip/hip_runtime.h>
#include <math.h>

typedef unsigned short u16;
typedef unsigned int u32;

#define N_ROWS 8192
#define DDIM 512
#define HDIM 1024
#define ODIM 512
#define NEXP 8
#define MAXPAIRS (N_ROWS * 2)          // 16384
#define MAXPOS (MAXPAIRS + NEXP * 128) // 17408 (per-expert segments 128-aligned)
#define MAXTILES (MAXPOS / 128)        // 136

// small-region word indices (in d_ws)
#define SM_CNT 0   // (unused since R19 partials)
#define SM_CUR 8   // 8 ints: scatter cursors
#define SM_AOFF 16 // 9 ints: aligned bucket offsets
#define SM_WORDS 64

using short8 = __attribute__((ext_vector_type(8))) short;
using float4v = __attribute__((ext_vector_type(4))) float;

__device__ __forceinline__ u16 f2bf(float f) {
    union { float f; u32 u; } v; v.f = f;
    u32 u = v.u;
    return (u16)((u + 0x7fffu + ((u >> 16) & 1u)) >> 16);
}

// async global->LDS, 16B per lane; HW places lane i at lds_base + i*16
__device__ __forceinline__ void async_copy16(u16* lds, const u16* g) {
    __builtin_amdgcn_global_load_lds(
        (const __attribute__((address_space(1))) void*)g,
        (__attribute__((address_space(3))) void*)lds, 16, 0, 0);
}

// ---------------- mega: gate + W1/W2 convert + owT + bucket/small/zeropage init ----------------
// R19: 7 launches -> 5. Gate is LDS-free (w_gate/w_noise read as coalesced
// float4 from L2; [d][e] row-major is already the perfect layout) and writes
// DENSE per-block partials (no pre-zeroed global atomics -> no ordering race
// with the init work living in the same grid). All paths share 4.2KB LDS.
#define MEGA_GATE 512   // N_ROWS/16
#define MEGA_W1 2048    // 2 float4/thread
#define MEGA_OWT 256
#define MEGA_BUCKET 68
#define MEGA_W2 2048    // 2 float4/thread
#define MEGA_BLOCKS (MEGA_GATE + MEGA_W1 + MEGA_OWT + MEGA_BUCKET + MEGA_W2) // 4932
__global__ __launch_bounds__(256) void mega_kernel(
    const float* __restrict__ x, const float* __restrict__ noise,
    const float* __restrict__ norm_w, const float* __restrict__ norm_b,
    const float* __restrict__ w_gate, const float* __restrict__ w_noise,
    const float* __restrict__ W1, const float* __restrict__ ow,
    const float* __restrict__ W2,
    u16* __restrict__ xnorm_bf, u16* __restrict__ x_bf,
    int* __restrict__ pair_expert, float* __restrict__ pair_gate,
    u16* __restrict__ W1b, u16* __restrict__ owT, u16* __restrict__ W2b,
    int* __restrict__ bucket_rows, int* __restrict__ small, float* __restrict__ zeropage,
    float* __restrict__ partial_g, float* __restrict__ partial_l, int* __restrict__ partial_c)
{
    __shared__ __align__(16) float sh[32 * 33 + 8];
    int b = blockIdx.x, tid = threadIdx.x;

    if (b >= MEGA_GATE) {
        int cb = b - MEGA_GATE;
        if (cb < MEGA_W1) { // W1 fp32->bf16, 2 float4/thread
            size_t i = (size_t)cb * 512 + tid;
#pragma unroll
            for (int t = 0; t < 2; t++, i += 256) {
                float4 v = ((const float4*)W1)[i];
                ushort4 o;
                o.x = f2bf(v.x); o.y = f2bf(v.y); o.z = f2bf(v.z); o.w = f2bf(v.w);
                ((ushort4*)W1b)[i] = o;
            }
        } else if (cb < MEGA_W1 + MEGA_OWT) { // ow transpose -> owT bf16
            float (*tile)[33] = (float(*)[33])sh;
            int t = cb - MEGA_W1;
            int bx = (t & 15) * 32, by = (t >> 4) * 32;
            int tx = tid & 31, ty = tid >> 5; // 32 x 8
            for (int r = ty; r < 32; r += 8) tile[r][tx] = ow[(size_t)(by + r) * ODIM + bx + tx];
            __syncthreads();
            for (int r = ty; r < 32; r += 8) owT[(size_t)(bx + r) * DDIM + by + tx] = f2bf(tile[tx][r]);
        } else if (cb < MEGA_W1 + MEGA_OWT + MEGA_BUCKET) { // bucket init (+small/zeropage in block 0)
            int lb = cb - MEGA_W1 - MEGA_OWT;
            int i = lb * 256 + tid;
            if (i < MAXPOS) bucket_rows[i] = -1;
            if (lb == 0) {
                if (tid < SM_WORDS) small[tid] = 0;
                zeropage[tid] = 0.f; zeropage[tid + 256] = 0.f;
            }
        } else { // W2 fp32->bf16, 2 float4/thread
            int j = cb - MEGA_W1 - MEGA_OWT - MEGA_BUCKET;
            size_t i = (size_t)j * 512 + tid;
#pragma unroll
            for (int t = 0; t < 2; t++, i += 256) {
                float4 v = ((const float4*)W2)[i];
                ushort4 o;
                o.x = f2bf(v.x); o.y = f2bf(v.y); o.z = f2bf(v.z); o.w = f2bf(v.w);
                ((ushort4*)W2b)[i] = o;
            }
        }
        return;
    }

    // ---- gate path: 16 rows/block, LDS-free weights, partials out ----
    float* lg = sh;                  // [16][17]
    float* blk_g = sh + 16 * 17;     // [8]
    float* blk_l = blk_g + 8;        // [8]
    int* blk_c = (int*)(blk_l + 8);  // [8]

    int wave = tid >> 6, lane = tid & 63;
    if (tid < 8) { blk_g[tid] = 0.f; blk_l[tid] = 0.f; blk_c[tid] = 0; }
    float nw[8], nb[8];
#pragma unroll
    for (int j = 0; j < 8; j++) { nw[j] = norm_w[j * 64 + lane]; nb[j] = norm_b[j * 64 + lane]; }

    bool l5 = (lane & 32) != 0, l4 = (lane & 16) != 0;
    bool l3 = (lane & 8) != 0, l2 = (lane & 4) != 0;

    for (int half = 0; half < 2; ++half) { // 2 rows at a time keeps VGPR ~100
        float xv[2][8], mu[2], rstd[2];
#pragma unroll
        for (int r = 0; r < 2; ++r) {
            int row = b * 16 + wave * 4 + half * 2 + r;
            const float* xr = x + (size_t)row * DDIM;
            float s = 0.f, s2 = 0.f;
#pragma unroll
            for (int j = 0; j < 8; j++) { float v = xr[j * 64 + lane]; xv[r][j] = v; s += v; s2 += v * v; }
#pragma unroll
            for (int o = 32; o; o >>= 1) { s += __shfl_xor(s, o, 64); s2 += __shfl_xor(s2, o, 64); }
            mu[r] = s * (1.f / DDIM);
            float var = s2 * (1.f / DDIM) - mu[r] * mu[r];
            rstd[r] = rsqrtf(var + 1e-6f);
        }
        float acc[2][16];
#pragma unroll
        for (int r = 0; r < 2; ++r)
#pragma unroll
            for (int e = 0; e < 16; e++) acc[r][e] = 0.f;
#pragma unroll
        for (int j = 0; j < 8; j++) {
            int d = j * 64 + lane;
            float4 wg0 = *(const float4*)&w_gate[d * 8];
            float4 wg1 = *(const float4*)&w_gate[d * 8 + 4];
            float4 wn0 = *(const float4*)&w_noise[d * 8];
            float4 wn1 = *(const float4*)&w_noise[d * 8 + 4];
#pragma unroll
            for (int r = 0; r < 2; ++r) {
                int row = b * 16 + wave * 4 + half * 2 + r;
                float v = (xv[r][j] - mu[r]) * rstd[r] * nw[j] + nb[j];
                xnorm_bf[(size_t)row * DDIM + d] = f2bf(v);
                x_bf[(size_t)row * DDIM + d] = f2bf(xv[r][j]);
                acc[r][0] += v * wg0.x; acc[r][1] += v * wg0.y;
                acc[r][2] += v * wg0.z; acc[r][3] += v * wg0.w;
                acc[r][4] += v * wg1.x; acc[r][5] += v * wg1.y;
                acc[r][6] += v * wg1.z; acc[r][7] += v * wg1.w;
                acc[r][8] += v * wn0.x; acc[r][9] += v * wn0.y;
                acc[r][10] += v * wn0.z; acc[r][11] += v * wn0.w;
                acc[r][12] += v * wn1.x; acc[r][13] += v * wn1.y;
                acc[r][14] += v * wn1.z; acc[r][15] += v * wn1.w;
            }
        }
        // value-split butterfly (R9-proven): lane l ends with full sum of value (l>>2)&15
#pragma unroll
        for (int r = 0; r < 2; ++r) {
            int lrow16 = wave * 4 + half * 2 + r;
            float t8[8];
#pragma unroll
            for (int v = 0; v < 8; v++) {
                float snd = l5 ? acc[r][v] : acc[r][v + 8];
                float kp = l5 ? acc[r][v + 8] : acc[r][v];
                t8[v] = kp + __shfl_xor(snd, 32, 64);
            }
            float t4[4];
#pragma unroll
            for (int v = 0; v < 4; v++) {
                float snd = l4 ? t8[v] : t8[v + 4];
                float kp = l4 ? t8[v + 4] : t8[v];
                t4[v] = kp + __shfl_xor(snd, 16, 64);
            }
            float t2[2];
#pragma unroll
            for (int v = 0; v < 2; v++) {
                float snd = l3 ? t4[v] : t4[v + 2];
                float kp = l3 ? t4[v + 2] : t4[v];
                t2[v] = kp + __shfl_xor(snd, 8, 64);
            }
            float snd = l2 ? t2[0] : t2[1];
            float kp = l2 ? t2[1] : t2[0];
            float t1 = kp + __shfl_xor(snd, 4, 64);
            t1 += __shfl_xor(t1, 2, 64);
            t1 += __shfl_xor(t1, 1, 64);
            if ((lane & 3) == 0) lg[lrow16 * 17 + ((lane >> 2) & 15)] = t1;
        }
    }
    __syncthreads();

    if (tid < 16) { // one lane per row: softplus + noisy + top3 + erf
        int row = b * 16 + tid;
        float cl[8], sd[8], nz[8];
#pragma unroll
        for (int e = 0; e < 8; e++) {
            cl[e] = lg[tid * 17 + e];
            float t = lg[tid * 17 + 8 + e];
            float sp = fmaxf(t, 0.f) + log1pf(expf(-fabsf(t))); // stable softplus
            sd[e] = sp + 0.01f;
            nz[e] = cl[e] + noise[(size_t)row * NEXP + e] * sd[e];
        }
        // top-3 (strict > = lowest-index tie-break, matching lax.top_k)
        int idx[3]; float val[3]; u32 msk = 0;
#pragma unroll
        for (int t = 0; t < 3; t++) {
            float best = -INFINITY; int bi = 0;
#pragma unroll
            for (int e = 0; e < 8; e++)
                if (!((msk >> e) & 1) && nz[e] > best) { best = nz[e]; bi = e; }
            idx[t] = bi; val[t] = best; msk |= 1u << bi;
        }
        float e1 = expf(val[1] - val[0]);
        float g0 = 1.f / (1.f + e1), g1 = e1 / (1.f + e1);
        float thr_in = val[2], thr_out = val[1];

        pair_expert[row * 2] = idx[0]; pair_gate[row * 2] = g0;
        pair_expert[row * 2 + 1] = idx[1]; pair_gate[row * 2 + 1] = g1;
        atomicAdd(&blk_g[idx[0]], g0); atomicAdd(&blk_g[idx[1]], g1);
        atomicAdd(&blk_c[idx[0]], 1); atomicAdd(&blk_c[idx[1]], 1);
#pragma unroll
        for (int e = 0; e < 8; e++) {
            float thr = (nz[e] > thr_in) ? thr_in : thr_out;
            float z = (cl[e] - thr) / sd[e];
            float p = 0.5f * (1.f + erff(z * 0.70710678118654752f));
            atomicAdd(&blk_l[e], p);
        }
    }
    __syncthreads();
    if (tid < 8) { // dense partials: fully overwritten, no init needed
        partial_g[b * 8 + tid] = blk_g[tid];
        partial_l[b * 8 + tid] = blk_l[tid];
        partial_c[b * 8 + tid] = blk_c[tid];
    }
}

// ---------------- scatter: partial reduce + prefix + loss/load + scatter + rowpos ----------------
__global__ __launch_bounds__(256) void scatter_kernel(
    const int* __restrict__ pair_expert, const float* __restrict__ pair_gate,
    const float* __restrict__ partial_g, const float* __restrict__ partial_l,
    const int* __restrict__ partial_c,
    int* __restrict__ small, int* __restrict__ bucket_rows, float* __restrict__ gate_by_pos,
    int* __restrict__ rowpos,
    float* __restrict__ out_loss, float* __restrict__ out_load)
{
    __shared__ int aoff[NEXP + 1];
    __shared__ int blk_cnt[NEXP];
    __shared__ int blk_base[NEXP];
    __shared__ int ired[256];
    __shared__ float fred[256];
    __shared__ float gsum[NEXP], lsum[NEXP];
    int tid = threadIdx.x;
    int e = tid & 7, g = tid >> 3;

    // every block reduces counts (needed for aoff)
    int s = 0;
    for (int k = g; k < MEGA_GATE; k += 32) s += partial_c[k * 8 + e];
    ired[tid] = s;
    if (tid < NEXP) blk_cnt[tid] = 0;
    __syncthreads();
    if (tid < 64) ired[tid] = ired[tid] + ired[tid + 64] + ired[tid + 128] + ired[tid + 192];
    __syncthreads();
    if (tid < 8) {
        int t = 0;
        for (int q = tid; q < 64; q += 8) t += ired[q];
        ired[tid] = t; // cnt per expert now in ired[0..7]
    }
    __syncthreads();
    if (tid == 0) {
        int acc = 0; aoff[0] = 0;
        for (int k = 0; k < NEXP; k++) { acc += (ired[k] + 127) & ~127; aoff[k + 1] = acc; }
    }
    __syncthreads();

    int p = blockIdx.x * 256 + tid;
    int pe = pair_expert[p];
    int local = atomicAdd(&blk_cnt[pe], 1);
    __syncthreads();
    if (tid < NEXP)
        blk_base[tid] = aoff[tid] + atomicAdd(&small[SM_CUR + tid], blk_cnt[tid]);
    if (blockIdx.x == 0 && tid < NEXP + 1) small[SM_AOFF + tid] = aoff[tid];
    __syncthreads();
    int pos = blk_base[pe] + local;
    bucket_rows[pos] = p >> 1;
    gate_by_pos[pos] = pair_gate[p];
    rowpos[p] = pos;

    if (blockIdx.x == 0) { // loss + load from partials
        float sg = 0.f, sl = 0.f;
        for (int k = g; k < MEGA_GATE; k += 32) { sg += partial_g[k * 8 + e]; sl += partial_l[k * 8 + e]; }
        fred[tid] = sg;
        __syncthreads();
        if (tid < 64) fred[tid] = fred[tid] + fred[tid + 64] + fred[tid + 128] + fred[tid + 192];
        __syncthreads();
        if (tid < 8) { float t = 0.f; for (int q = tid; q < 64; q += 8) t += fred[q]; gsum[tid] = t; }
        __syncthreads();
        fred[tid] = sl;
        __syncthreads();
        if (tid < 64) fred[tid] = fred[tid] + fred[tid + 64] + fred[tid + 128] + fred[tid + 192];
        __syncthreads();
        if (tid < 8) { float t = 0.f; for (int q = tid; q < 64; q += 8) t += fred[q]; lsum[tid] = t; }
        __syncthreads();
        if (tid == 0) {
            float cv[2];
            for (int t = 0; t < 2; t++) {
                const float* v = t ? lsum : gsum;
                float m = 0.f;
                for (int k = 0; k < NEXP; k++) m += v[k];
                m *= (1.f / NEXP);
                float var = 0.f;
                for (int k = 0; k < NEXP; k++) { float d = v[k] - m; var += d * d; }
                var *= (1.f / NEXP);
                cv[t] = var / (m * m + 1e-10f);
            }
            out_loss[0] = 0.01f * (cv[0] + cv[1]);
            int tot = 0;
            for (int k = 0; k < NEXP; k++) tot += ired[k];
            float inv = 1.f / (float)tot;
            for (int k = 0; k < NEXP; k++) out_load[k] = (float)ired[k] * inv;
        }
    }
}

// ---------------- gemmA: mode0 + mode2 (R9-identical) ----------------
__global__ __launch_bounds__(256) void gemmA_kernel(
    const u16* __restrict__ xnorm, const u16* __restrict__ W1b,
    const u16* __restrict__ xbf, const u16* __restrict__ owT,
    const int* __restrict__ bucket_rows, const int* __restrict__ small,
    const float* __restrict__ b1, const u16* __restrict__ zeropage,
    u16* __restrict__ a_buf, float* __restrict__ y)
{
    constexpr int KD = 512;
    __shared__ __align__(16) u16 As[128 * 64];
    __shared__ __align__(16) u16 Bs[128 * 64];

    int tid = threadIdx.x;
    if (blockIdx.y >= 8) { // ---- mode2: x_bf @ owT^T, 128x128, BK32 2-buffer, plain stores ----
        int j = (blockIdx.y - 8) * 136 + blockIdx.x;
        if (j >= 256) return;
        int base = (j >> 2) * 128, bn = (j & 3) * 128;
        int wave = tid >> 6, lane = tid & 63;
        const int lrow = lane >> 2;
        const int kcol = (((lane & 3) ^ ((lane >> 3) & 3)) * 8);
        const int trow = wave * 32 + lrow;
        int wm = (wave & 1) * 64, wn = (wave >> 1) * 64;
        int fr = lane & 15, kq = lane >> 4;
        const int kg = ((kq ^ ((fr >> 1) & 3)) * 8);
        const u16* ga0 = xbf + (size_t)(base + trow) * KD + kcol;
        const u16* ga1 = xbf + (size_t)(base + trow + 16) * KD + kcol;
        const u16* gb0 = owT + (size_t)(bn + trow) * KD + kcol;
        const u16* gb1 = owT + (size_t)(bn + trow + 16) * KD + kcol;
        u16* As2 = (u16*)As; u16* Bs2 = (u16*)Bs; // reused as [2][128*32]
        const int ofA0 = (wave * 32) * 32, ofA1 = (wave * 32 + 16) * 32;

        float4v acc[4][4];
#pragma unroll
        for (int i = 0; i < 4; i++)
#pragma unroll
            for (int jj = 0; jj < 4; jj++) acc[i][jj] = (float4v){0.f, 0.f, 0.f, 0.f};

        async_copy16(As2 + ofA0, ga0); async_copy16(As2 + ofA1, ga1);
        async_copy16(Bs2 + ofA0, gb0); async_copy16(Bs2 + ofA1, gb1);
        __syncthreads();
        int cur = 0;
        for (int t = 0; t < 16; ++t) {
            int nxt = cur ^ 1;
            if (t + 1 < 16) {
                int k1 = (t + 1) << 5;
                async_copy16(As2 + nxt * 4096 + ofA0, ga0 + k1);
                async_copy16(As2 + nxt * 4096 + ofA1, ga1 + k1);
                async_copy16(Bs2 + nxt * 4096 + ofA0, gb0 + k1);
                async_copy16(Bs2 + nxt * 4096 + ofA1, gb1 + k1);
            }
            short8 af[4], bf[4];
#pragma unroll
            for (int mt = 0; mt < 4; mt++) af[mt] = *(const short8*)&As2[cur * 4096 + (wm + mt * 16 + fr) * 32 + kg];
#pragma unroll
            for (int nt = 0; nt < 4; nt++) bf[nt] = *(const short8*)&Bs2[cur * 4096 + (wn + nt * 16 + fr) * 32 + kg];
#pragma unroll
            for (int mt = 0; mt < 4; mt++)
#pragma unroll
                for (int nt = 0; nt < 4; nt++)
                    acc[mt][nt] = __builtin_amdgcn_mfma_f32_16x16x32_bf16(af[mt], bf[nt], acc[mt][nt], 0, 0, 0);
            __syncthreads();
            cur = nxt;
        }
        int rbase = (lane >> 4) * 4, c16 = lane & 15;
#pragma unroll
        for (int mt = 0; mt < 4; mt++) {
            int gm = base + wm + mt * 16 + rbase;
#pragma unroll
            for (int nt = 0; nt < 4; nt++) {
                int gn = bn + wn + nt * 16 + c16;
#pragma unroll
                for (int r = 0; r < 4; r++)
                    y[(size_t)(gm + r) * ODIM + gn] = acc[mt][nt][r];
            }
        }
        return;
    }

    // ---- mode0: BK64 swizzled 128x128 (R5 proven core) ----
    int base = blockIdx.x * 128;
    if (base >= small[SM_AOFF + 8]) return;
    int e = 0;
    while (e < 7 && base >= small[SM_AOFF + e + 1]) ++e;
    int bn = blockIdx.y * 128;
    const u16* Bsel = W1b + (size_t)e * HDIM * KD;

    int wave = tid >> 6, lane = tid & 63;
    int lr = lane >> 3;                 // row within 8-row chunk
    int lc = ((lane & 7) ^ lr) * 8;     // swizzled col-group (elements)

    const u16* ga[4]; const u16* gb[4];
    u16* la[4]; u16* lb[4];
#pragma unroll
    for (int c = 0; c < 4; c++) {
        int tr = wave * 32 + c * 8;     // chunk base row
        int r0 = bucket_rows[base + tr + lr];
        ga[c] = ((r0 < 0) ? zeropage : xnorm + (size_t)r0 * KD) + lc;
        gb[c] = Bsel + (size_t)(bn + tr + lr) * KD + lc;
        la[c] = &As[tr * 64];
        lb[c] = &Bs[tr * 64];
    }

    int wm = (wave & 1) * 64, wn = (wave >> 1) * 64;
    int fr = lane & 15, kq = lane >> 4, f7 = fr & 7;

    float4v acc[4][4];
#pragma unroll
    for (int i = 0; i < 4; i++)
#pragma unroll
        for (int j = 0; j < 4; j++) acc[i][j] = (float4v){0.f, 0.f, 0.f, 0.f};

    for (int k0 = 0; k0 < KD; k0 += 64) {
        __syncthreads();
#pragma unroll
        for (int c = 0; c < 4; c++) async_copy16(la[c], ga[c] + k0);
#pragma unroll
        for (int c = 0; c < 4; c++) async_copy16(lb[c], gb[c] + k0);
        __syncthreads();
        short8 af[4][2], bf[4][2];
#pragma unroll
        for (int mt = 0; mt < 4; mt++)
#pragma unroll
            for (int kh = 0; kh < 2; kh++)
                af[mt][kh] = *(const short8*)&As[(wm + mt * 16 + fr) * 64 + (((kq + 4 * kh) ^ f7) * 8)];
#pragma unroll
        for (int nt = 0; nt < 4; nt++)
#pragma unroll
            for (int kh = 0; kh < 2; kh++)
                bf[nt][kh] = *(const short8*)&Bs[(wn + nt * 16 + fr) * 64 + (((kq + 4 * kh) ^ f7) * 8)];
#pragma unroll
        for (int mt = 0; mt < 4; mt++)
#pragma unroll
            for (int nt = 0; nt < 4; nt++) {
                acc[mt][nt] = __builtin_amdgcn_mfma_f32_16x16x32_bf16(af[mt][0], bf[nt][0], acc[mt][nt], 0, 0, 0);
                acc[mt][nt] = __builtin_amdgcn_mfma_f32_16x16x32_bf16(af[mt][1], bf[nt][1], acc[mt][nt], 0, 0, 0);
            }
    }

    // epilogue: C/D layout col=lane&15, row=(lane>>4)*4+reg (m89-verified)
    int rbase = (lane >> 4) * 4, c16 = lane & 15;
#pragma unroll
    for (int nt = 0; nt < 4; nt++) {
        int gn = bn + wn + nt * 16 + c16;
        float bv = b1[e * HDIM + gn];
#pragma unroll
        for (int mt = 0; mt < 4; mt++) {
            int gm = base + wm + mt * 16 + rbase;
#pragma unroll
            for (int r = 0; r < 4; r++) {
                float h = acc[mt][nt][r] + bv;
                float a = h * __builtin_amdgcn_rcpf(1.f + __expf(-h)); // fast SiLU
                a_buf[(size_t)(gm + r) * HDIM + gn] = f2bf(a);
            }
        }
    }
}

// ---------------- gemmB: expert down-proj, DENSE PLAIN STORES (R9-identical) ----------------
__global__ __launch_bounds__(512) void gemmB_kernel(
    const u16* __restrict__ a_buf, const u16* __restrict__ W2b,
    const int* __restrict__ bucket_rows, const int* __restrict__ small,
    const float* __restrict__ b2, const float* __restrict__ gate_by_pos,
    float* __restrict__ ye)
{
    constexpr int KD = 1024;
    __shared__ __align__(16) u16 As[2][128 * 32];
    __shared__ __align__(16) u16 Bs[2][256 * 32];

    int tid = threadIdx.x;
    int wave = tid >> 6, lane = tid & 63;
    const int lrow = lane >> 2;                              // row within 16-row chunk
    const int kcol = (((lane & 3) ^ ((lane >> 3) & 3)) * 8); // pre-swizzled global col-group
    int wm = (wave >> 2) * 64, wn = (wave & 3) * 64;         // wave -> 64x64 of 128x256
    int fr = lane & 15, kq = lane >> 4;
    const int kg = ((kq ^ ((fr >> 1) & 3)) * 8);             // swizzled read group

    int base = blockIdx.x * 128;
    if (base >= small[SM_AOFF + 8]) return;
    int e = 0;
    while (e < 7 && base >= small[SM_AOFF + e + 1]) ++e;
    int bn = blockIdx.y * 256;

    const u16* ga0 = a_buf + (size_t)(base + wave * 16 + lrow) * KD + kcol;
    const u16* Bsel = W2b + (size_t)e * ODIM * KD;
    const u16* gb0 = Bsel + (size_t)(bn + wave * 32 + lrow) * KD + kcol;
    const u16* gb1 = Bsel + (size_t)(bn + wave * 32 + 16 + lrow) * KD + kcol;
    const int ofA = (wave * 16) * 32;
    const int ofB0 = (wave * 32) * 32;
    const int ofB1 = (wave * 32 + 16) * 32;

    float4v acc[4][4];
#pragma unroll
    for (int i = 0; i < 4; i++)
#pragma unroll
        for (int j = 0; j < 4; j++) acc[i][j] = (float4v){0.f, 0.f, 0.f, 0.f};

    constexpr int nk = KD >> 5; // 32
    async_copy16(&As[0][ofA], ga0);
    async_copy16(&Bs[0][ofB0], gb0);
    async_copy16(&Bs[0][ofB1], gb1);
    __syncthreads();

    int cur = 0;
    for (int t = 0; t < nk; ++t) {
        int nxt = cur ^ 1;
        if (t + 1 < nk) { // prefetch next tile; in flight across compute
            int k1 = (t + 1) << 5;
            async_copy16(&As[nxt][ofA], ga0 + k1);
            async_copy16(&Bs[nxt][ofB0], gb0 + k1);
            async_copy16(&Bs[nxt][ofB1], gb1 + k1);
        }
        short8 af[4], bf[4];
#pragma unroll
        for (int mt = 0; mt < 4; mt++) af[mt] = *(const short8*)&As[cur][(wm + mt * 16 + fr) * 32 + kg];
#pragma unroll
        for (int nt = 0; nt < 4; nt++) bf[nt] = *(const short8*)&Bs[cur][(wn + nt * 16 + fr) * 32 + kg];
#pragma unroll
        for (int mt = 0; mt < 4; mt++)
#pragma unroll
            for (int nt = 0; nt < 4; nt++)
                acc[mt][nt] = __builtin_amdgcn_mfma_f32_16x16x32_bf16(af[mt], bf[nt], acc[mt][nt], 0, 0, 0);
        __syncthreads();
        cur = nxt;
    }

    int rbase = (lane >> 4) * 4, c16 = lane & 15;
#pragma unroll
    for (int mt = 0; mt < 4; mt++) {
        int pos0 = base + wm + mt * 16 + rbase;
        int rows[4]; float gs[4];
#pragma unroll
        for (int r = 0; r < 4; r++) { rows[r] = bucket_rows[pos0 + r]; gs[r] = gate_by_pos[pos0 + r]; }
#pragma unroll
        for (int nt = 0; nt < 4; nt++) {
            int gn = bn + wn + nt * 16 + c16;
            float b2v = b2[e * ODIM + gn];
#pragma unroll
            for (int r = 0; r < 4; r++) {
                if (rows[r] >= 0)
                    ye[(size_t)(pos0 + r) * ODIM + gn] = gs[r] * (acc[mt][nt][r] + b2v);
            }
        }
    }
}

// ---------------- combine: y[row] = y_mode2[row] + ye[pos0] + ye[pos1] ----------------
__global__ __launch_bounds__(256) void combine_kernel(
    const float* __restrict__ ye, const int* __restrict__ rowpos,
    float* __restrict__ y)
{
    int tid = threadIdx.x;
    int row = blockIdx.x * 16 + (tid >> 4);
    int c0 = (tid & 15) * 32;
    int p0 = rowpos[row * 2];
    int p1 = rowpos[row * 2 + 1];
    const float4* e0 = (const float4*)(ye + (size_t)p0 * ODIM + c0);
    const float4* e1 = (const float4*)(ye + (size_t)p1 * ODIM + c0);
    float4* yp = (float4*)(y + (size_t)row * ODIM + c0);
#pragma unroll
    for (int i = 0; i < 8; i++) {
        float4 a = yp[i], b = e0[i], c = e1[i];
        a.x += b.x + c.x; a.y += b.y + c.y; a.z += b.z + c.z; a.w += b.w + c.w;
        yp[i] = a;
    }
}

extern "C" void kernel_launch(void* const* d_in, const int* in_sizes, int n_in,
                              void* d_out, int out_size, void* d_ws, size_t ws_size,
                              hipStream_t stream)
{
    (void)in_sizes; (void)n_in; (void)out_size; (void)ws_size;
    const float* x = (const float*)d_in[0];
    // d_in[1] x_offsets, d_in[2] max_seq_len: unused by the reference math
    const float* noise = (const float*)d_in[3];
    const float* norm_w = (const float*)d_in[4];
    const float* norm_b = (const float*)d_in[5];
    const float* w_gate = (const float*)d_in[6];
    const float* w_noise = (const float*)d_in[7];
    const float* W1 = (const float*)d_in[8];
    const float* b1 = (const float*)d_in[9];
    const float* W2 = (const float*)d_in[10];
    const float* b2 = (const float*)d_in[11];
    const float* ow = (const float*)d_in[12];

    float* y = (float*)d_out;
    float* out_loss = y + (size_t)N_ROWS * ODIM;
    float* out_load = out_loss + 1;

    char* ws = (char*)d_ws;
    size_t off = 0;
    auto alloc = [&](size_t b) { size_t p = off; off = (off + b + 255) & ~(size_t)255; return p; };
    u16* xnorm_bf = (u16*)(ws + alloc((size_t)N_ROWS * DDIM * 2));
    u16* x_bf     = (u16*)(ws + alloc((size_t)N_ROWS * DDIM * 2));
    u16* W1b      = (u16*)(ws + alloc((size_t)NEXP * HDIM * DDIM * 2));
    u16* W2b      = (u16*)(ws + alloc((size_t)NEXP * ODIM * HDIM * 2));
    u16* owT      = (u16*)(ws + alloc((size_t)DDIM * ODIM * 2));
    u16* a_buf    = (u16*)(ws + alloc((size_t)MAXPOS * HDIM * 2));
    float* ye     = (float*)(ws + alloc((size_t)MAXPOS * ODIM * 4));
    int* pair_expert = (int*)(ws + alloc((size_t)MAXPAIRS * 4));
    float* pair_gate = (float*)(ws + alloc((size_t)MAXPAIRS * 4));
    float* gate_by_pos = (float*)(ws + alloc((size_t)MAXPOS * 4));
    int* bucket_rows = (int*)(ws + alloc((size_t)MAXPOS * 4));
    int* rowpos      = (int*)(ws + alloc((size_t)MAXPAIRS * 4));
    int* small       = (int*)(ws + alloc(SM_WORDS * 4));
    float* zeropage  = (float*)(ws + alloc(2048));
    float* partial_g = (float*)(ws + alloc((size_t)MEGA_GATE * NEXP * 4));
    float* partial_l = (float*)(ws + alloc((size_t)MEGA_GATE * NEXP * 4));
    int* partial_c   = (int*)(ws + alloc((size_t)MEGA_GATE * NEXP * 4));

    mega_kernel<<<MEGA_BLOCKS, 256, 0, stream>>>(
        x, noise, norm_w, norm_b, w_gate, w_noise, W1, ow, W2,
        xnorm_bf, x_bf, pair_expert, pair_gate, W1b, owT, W2b,
        bucket_rows, small, zeropage, partial_g, partial_l, partial_c);
    scatter_kernel<<<MAXPAIRS / 256, 256, 0, stream>>>(pair_expert, pair_gate,
                                                       partial_g, partial_l, partial_c,
                                                       small, bucket_rows, gate_by_pos, rowpos,
                                                       out_loss, out_load);
    gemmA_kernel<<<dim3(MAXTILES, 8 + 2), 256, 0, stream>>>(xnorm_bf, W1b,
                                                            x_bf, owT, bucket_rows, small, b1,
                                                            (const u16*)zeropage, a_buf, y);
    gemmB_kernel<<<dim3(MAXTILES, 2), 512, 0, stream>>>(a_buf, W2b, bucket_rows,
                                                        small, b2, gate_by_pos, ye);
    combine_kernel<<<N_ROWS / 16, 256, 0, stream>>>(ye, rowpos, y);
}

// Round 11
// 234.505 us; speedup vs baseline: 1.1166x; 1.0146x over previous
//
#include <hip/hip_runtime.h>
#include <math.h>

typedef unsigned short u16;
typedef unsigned int u32;

#define N_ROWS 8192
#define DDIM 512
#define HDIM 1024
#define ODIM 512
#define NEXP 8
#define MAXPAIRS (N_ROWS * 2)          // 16384
#define MAXPOS (MAXPAIRS + NEXP * 128) // 17408 (per-expert segments 128-aligned)
#define MAXTILES (MAXPOS / 128)        // 136

// small-region word indices (in d_ws)
#define SM_CNT 0   // (unused since R19 partials)
#define SM_CUR 8   // 8 ints: scatter cursors
#define SM_AOFF 16 // 9 ints: aligned bucket offsets
#define SM_WORDS 64

using short8 = __attribute__((ext_vector_type(8))) short;
using float4v = __attribute__((ext_vector_type(4))) float;

__device__ __forceinline__ u16 f2bf(float f) {
    union { float f; u32 u; } v; v.f = f;
    u32 u = v.u;
    return (u16)((u + 0x7fffu + ((u >> 16) & 1u)) >> 16);
}

// async global->LDS, 16B per lane; HW places lane i at lds_base + i*16
__device__ __forceinline__ void async_copy16(u16* lds, const u16* g) {
    __builtin_amdgcn_global_load_lds(
        (const __attribute__((address_space(1))) void*)g,
        (__attribute__((address_space(3))) void*)lds, 16, 0, 0);
}

// ---------------- mega: gate + W1/W2 convert + owT + bucket/small/zeropage init ----------------
// R19-proven: gate is LDS-free, writes DENSE per-block partials.
#define MEGA_GATE 512   // N_ROWS/16
#define MEGA_W1 2048    // 2 float4/thread
#define MEGA_OWT 256
#define MEGA_BUCKET 68
#define MEGA_W2 2048    // 2 float4/thread
#define MEGA_BLOCKS (MEGA_GATE + MEGA_W1 + MEGA_OWT + MEGA_BUCKET + MEGA_W2) // 4932
__global__ __launch_bounds__(256) void mega_kernel(
    const float* __restrict__ x, const float* __restrict__ noise,
    const float* __restrict__ norm_w, const float* __restrict__ norm_b,
    const float* __restrict__ w_gate, const float* __restrict__ w_noise,
    const float* __restrict__ W1, const float* __restrict__ ow,
    const float* __restrict__ W2,
    u16* __restrict__ xnorm_bf, u16* __restrict__ x_bf,
    int* __restrict__ pair_expert, float* __restrict__ pair_gate,
    u16* __restrict__ W1b, u16* __restrict__ owT, u16* __restrict__ W2b,
    int* __restrict__ bucket_rows, int* __restrict__ small, float* __restrict__ zeropage,
    float* __restrict__ partial_g, float* __restrict__ partial_l, int* __restrict__ partial_c)
{
    __shared__ __align__(16) float sh[32 * 33 + 8];
    int b = blockIdx.x, tid = threadIdx.x;

    if (b >= MEGA_GATE) {
        int cb = b - MEGA_GATE;
        if (cb < MEGA_W1) { // W1 fp32->bf16, 2 float4/thread
            size_t i = (size_t)cb * 512 + tid;
#pragma unroll
            for (int t = 0; t < 2; t++, i += 256) {
                float4 v = ((const float4*)W1)[i];
                ushort4 o;
                o.x = f2bf(v.x); o.y = f2bf(v.y); o.z = f2bf(v.z); o.w = f2bf(v.w);
                ((ushort4*)W1b)[i] = o;
            }
        } else if (cb < MEGA_W1 + MEGA_OWT) { // ow transpose -> owT bf16
            float (*tile)[33] = (float(*)[33])sh;
            int t = cb - MEGA_W1;
            int bx = (t & 15) * 32, by = (t >> 4) * 32;
            int tx = tid & 31, ty = tid >> 5; // 32 x 8
            for (int r = ty; r < 32; r += 8) tile[r][tx] = ow[(size_t)(by + r) * ODIM + bx + tx];
            __syncthreads();
            for (int r = ty; r < 32; r += 8) owT[(size_t)(bx + r) * DDIM + by + tx] = f2bf(tile[tx][r]);
        } else if (cb < MEGA_W1 + MEGA_OWT + MEGA_BUCKET) { // bucket init (+small/zeropage in block 0)
            int lb = cb - MEGA_W1 - MEGA_OWT;
            int i = lb * 256 + tid;
            if (i < MAXPOS) bucket_rows[i] = -1;
            if (lb == 0) {
                if (tid < SM_WORDS) small[tid] = 0;
                zeropage[tid] = 0.f; zeropage[tid + 256] = 0.f;
            }
        } else { // W2 fp32->bf16, 2 float4/thread
            int j = cb - MEGA_W1 - MEGA_OWT - MEGA_BUCKET;
            size_t i = (size_t)j * 512 + tid;
#pragma unroll
            for (int t = 0; t < 2; t++, i += 256) {
                float4 v = ((const float4*)W2)[i];
                ushort4 o;
                o.x = f2bf(v.x); o.y = f2bf(v.y); o.z = f2bf(v.z); o.w = f2bf(v.w);
                ((ushort4*)W2b)[i] = o;
            }
        }
        return;
    }

    // ---- gate path: 16 rows/block, LDS-free weights, partials out ----
    float* lg = sh;                  // [16][17]
    float* blk_g = sh + 16 * 17;     // [8]
    float* blk_l = blk_g + 8;        // [8]
    int* blk_c = (int*)(blk_l + 8);  // [8]

    int wave = tid >> 6, lane = tid & 63;
    if (tid < 8) { blk_g[tid] = 0.f; blk_l[tid] = 0.f; blk_c[tid] = 0; }
    float nw[8], nb[8];
#pragma unroll
    for (int j = 0; j < 8; j++) { nw[j] = norm_w[j * 64 + lane]; nb[j] = norm_b[j * 64 + lane]; }

    bool l5 = (lane & 32) != 0, l4 = (lane & 16) != 0;
    bool l3 = (lane & 8) != 0, l2 = (lane & 4) != 0;

    for (int half = 0; half < 2; ++half) { // 2 rows at a time keeps VGPR ~100
        float xv[2][8], mu[2], rstd[2];
#pragma unroll
        for (int r = 0; r < 2; ++r) {
            int row = b * 16 + wave * 4 + half * 2 + r;
            const float* xr = x + (size_t)row * DDIM;
            float s = 0.f, s2 = 0.f;
#pragma unroll
            for (int j = 0; j < 8; j++) { float v = xr[j * 64 + lane]; xv[r][j] = v; s += v; s2 += v * v; }
#pragma unroll
            for (int o = 32; o; o >>= 1) { s += __shfl_xor(s, o, 64); s2 += __shfl_xor(s2, o, 64); }
            mu[r] = s * (1.f / DDIM);
            float var = s2 * (1.f / DDIM) - mu[r] * mu[r];
            rstd[r] = rsqrtf(var + 1e-6f);
        }
        float acc[2][16];
#pragma unroll
        for (int r = 0; r < 2; ++r)
#pragma unroll
            for (int e = 0; e < 16; e++) acc[r][e] = 0.f;
#pragma unroll
        for (int j = 0; j < 8; j++) {
            int d = j * 64 + lane;
            float4 wg0 = *(const float4*)&w_gate[d * 8];
            float4 wg1 = *(const float4*)&w_gate[d * 8 + 4];
            float4 wn0 = *(const float4*)&w_noise[d * 8];
            float4 wn1 = *(const float4*)&w_noise[d * 8 + 4];
#pragma unroll
            for (int r = 0; r < 2; ++r) {
                int row = b * 16 + wave * 4 + half * 2 + r;
                float v = (xv[r][j] - mu[r]) * rstd[r] * nw[j] + nb[j];
                xnorm_bf[(size_t)row * DDIM + d] = f2bf(v);
                x_bf[(size_t)row * DDIM + d] = f2bf(xv[r][j]);
                acc[r][0] += v * wg0.x; acc[r][1] += v * wg0.y;
                acc[r][2] += v * wg0.z; acc[r][3] += v * wg0.w;
                acc[r][4] += v * wg1.x; acc[r][5] += v * wg1.y;
                acc[r][6] += v * wg1.z; acc[r][7] += v * wg1.w;
                acc[r][8] += v * wn0.x; acc[r][9] += v * wn0.y;
                acc[r][10] += v * wn0.z; acc[r][11] += v * wn0.w;
                acc[r][12] += v * wn1.x; acc[r][13] += v * wn1.y;
                acc[r][14] += v * wn1.z; acc[r][15] += v * wn1.w;
            }
        }
        // value-split butterfly (R9-proven): lane l ends with full sum of value (l>>2)&15
#pragma unroll
        for (int r = 0; r < 2; ++r) {
            int lrow16 = wave * 4 + half * 2 + r;
            float t8[8];
#pragma unroll
            for (int v = 0; v < 8; v++) {
                float snd = l5 ? acc[r][v] : acc[r][v + 8];
                float kp = l5 ? acc[r][v + 8] : acc[r][v];
                t8[v] = kp + __shfl_xor(snd, 32, 64);
            }
            float t4[4];
#pragma unroll
            for (int v = 0; v < 4; v++) {
                float snd = l4 ? t8[v] : t8[v + 4];
                float kp = l4 ? t8[v + 4] : t8[v];
                t4[v] = kp + __shfl_xor(snd, 16, 64);
            }
            float t2[2];
#pragma unroll
            for (int v = 0; v < 2; v++) {
                float snd = l3 ? t4[v] : t4[v + 2];
                float kp = l3 ? t4[v + 2] : t4[v];
                t2[v] = kp + __shfl_xor(snd, 8, 64);
            }
            float snd = l2 ? t2[0] : t2[1];
            float kp = l2 ? t2[1] : t2[0];
            float t1 = kp + __shfl_xor(snd, 4, 64);
            t1 += __shfl_xor(t1, 2, 64);
            t1 += __shfl_xor(t1, 1, 64);
            if ((lane & 3) == 0) lg[lrow16 * 17 + ((lane >> 2) & 15)] = t1;
        }
    }
    __syncthreads();

    if (tid < 16) { // one lane per row: softplus + noisy + top3 + erf
        int row = b * 16 + tid;
        float cl[8], sd[8], nz[8];
#pragma unroll
        for (int e = 0; e < 8; e++) {
            cl[e] = lg[tid * 17 + e];
            float t = lg[tid * 17 + 8 + e];
            float sp = fmaxf(t, 0.f) + log1pf(expf(-fabsf(t))); // stable softplus
            sd[e] = sp + 0.01f;
            nz[e] = cl[e] + noise[(size_t)row * NEXP + e] * sd[e];
        }
        // top-3 (strict > = lowest-index tie-break, matching lax.top_k)
        int idx[3]; float val[3]; u32 msk = 0;
#pragma unroll
        for (int t = 0; t < 3; t++) {
            float best = -INFINITY; int bi = 0;
#pragma unroll
            for (int e = 0; e < 8; e++)
                if (!((msk >> e) & 1) && nz[e] > best) { best = nz[e]; bi = e; }
            idx[t] = bi; val[t] = best; msk |= 1u << bi;
        }
        float e1 = expf(val[1] - val[0]);
        float g0 = 1.f / (1.f + e1), g1 = e1 / (1.f + e1);
        float thr_in = val[2], thr_out = val[1];

        pair_expert[row * 2] = idx[0]; pair_gate[row * 2] = g0;
        pair_expert[row * 2 + 1] = idx[1]; pair_gate[row * 2 + 1] = g1;
        atomicAdd(&blk_g[idx[0]], g0); atomicAdd(&blk_g[idx[1]], g1);
        atomicAdd(&blk_c[idx[0]], 1); atomicAdd(&blk_c[idx[1]], 1);
#pragma unroll
        for (int e = 0; e < 8; e++) {
            float thr = (nz[e] > thr_in) ? thr_in : thr_out;
            float z = (cl[e] - thr) / sd[e];
            float p = 0.5f * (1.f + erff(z * 0.70710678118654752f));
            atomicAdd(&blk_l[e], p);
        }
    }
    __syncthreads();
    if (tid < 8) { // dense partials: fully overwritten, no init needed
        partial_g[b * 8 + tid] = blk_g[tid];
        partial_l[b * 8 + tid] = blk_l[tid];
        partial_c[b * 8 + tid] = blk_c[tid];
    }
}

// ---------------- scatter: partial reduce + prefix + loss/load + scatter + rowpos ----------------
__global__ __launch_bounds__(256) void scatter_kernel(
    const int* __restrict__ pair_expert, const float* __restrict__ pair_gate,
    const float* __restrict__ partial_g, const float* __restrict__ partial_l,
    const int* __restrict__ partial_c,
    int* __restrict__ small, int* __restrict__ bucket_rows, float* __restrict__ gate_by_pos,
    int* __restrict__ rowpos,
    float* __restrict__ out_loss, float* __restrict__ out_load)
{
    __shared__ int aoff[NEXP + 1];
    __shared__ int blk_cnt[NEXP];
    __shared__ int blk_base[NEXP];
    __shared__ int ired[256];
    __shared__ float fred[256];
    __shared__ float gsum[NEXP], lsum[NEXP];
    int tid = threadIdx.x;
    int e = tid & 7, g = tid >> 3;

    // every block reduces counts (needed for aoff)
    int s = 0;
    for (int k = g; k < MEGA_GATE; k += 32) s += partial_c[k * 8 + e];
    ired[tid] = s;
    if (tid < NEXP) blk_cnt[tid] = 0;
    __syncthreads();
    if (tid < 64) ired[tid] = ired[tid] + ired[tid + 64] + ired[tid + 128] + ired[tid + 192];
    __syncthreads();
    if (tid < 8) {
        int t = 0;
        for (int q = tid; q < 64; q += 8) t += ired[q];
        ired[tid] = t; // cnt per expert now in ired[0..7]
    }
    __syncthreads();
    if (tid == 0) {
        int acc = 0; aoff[0] = 0;
        for (int k = 0; k < NEXP; k++) { acc += (ired[k] + 127) & ~127; aoff[k + 1] = acc; }
    }
    __syncthreads();

    int p = blockIdx.x * 256 + tid;
    int pe = pair_expert[p];
    int local = atomicAdd(&blk_cnt[pe], 1);
    __syncthreads();
    if (tid < NEXP)
        blk_base[tid] = aoff[tid] + atomicAdd(&small[SM_CUR + tid], blk_cnt[tid]);
    if (blockIdx.x == 0 && tid < NEXP + 1) small[SM_AOFF + tid] = aoff[tid];
    __syncthreads();
    int pos = blk_base[pe] + local;
    bucket_rows[pos] = p >> 1;
    gate_by_pos[pos] = pair_gate[p];
    rowpos[p] = pos;

    if (blockIdx.x == 0) { // loss + load from partials
        float sg = 0.f, sl = 0.f;
        for (int k = g; k < MEGA_GATE; k += 32) { sg += partial_g[k * 8 + e]; sl += partial_l[k * 8 + e]; }
        fred[tid] = sg;
        __syncthreads();
        if (tid < 64) fred[tid] = fred[tid] + fred[tid + 64] + fred[tid + 128] + fred[tid + 192];
        __syncthreads();
        if (tid < 8) { float t = 0.f; for (int q = tid; q < 64; q += 8) t += fred[q]; gsum[tid] = t; }
        __syncthreads();
        fred[tid] = sl;
        __syncthreads();
        if (tid < 64) fred[tid] = fred[tid] + fred[tid + 64] + fred[tid + 128] + fred[tid + 192];
        __syncthreads();
        if (tid < 8) { float t = 0.f; for (int q = tid; q < 64; q += 8) t += fred[q]; lsum[tid] = t; }
        __syncthreads();
        if (tid == 0) {
            float cv[2];
            for (int t = 0; t < 2; t++) {
                const float* v = t ? lsum : gsum;
                float m = 0.f;
                for (int k = 0; k < NEXP; k++) m += v[k];
                m *= (1.f / NEXP);
                float var = 0.f;
                for (int k = 0; k < NEXP; k++) { float d = v[k] - m; var += d * d; }
                var *= (1.f / NEXP);
                cv[t] = var / (m * m + 1e-10f);
            }
            out_loss[0] = 0.01f * (cv[0] + cv[1]);
            int tot = 0;
            for (int k = 0; k < NEXP; k++) tot += ired[k];
            float inv = 1.f / (float)tot;
            for (int k = 0; k < NEXP; k++) out_load[k] = (float)ired[k] * inv;
        }
    }
}

// ---------------- gemmA: mode0 + mode2, R20: gemmB-clone fat-tile core ----------------
// 512 thr, 128x256 tile, BK32 2-buffer syncthreads (proven in gemmB R14/R16).
// y<4:  gathered x_norm @ W1[e]^T (bn = y*256 of HDIM), +b1, SiLU -> a_buf bf16.
//       A staged 4x instead of 8x (209 vs 278 MB), half the block prologues.
// y==4: mode2 x_bf @ owT^T (j=blockIdx.x<128: 64 row-tiles x 2 col-tiles),
//       plain fp32 stores to y (combine adds expert terms).
__global__ __launch_bounds__(512) void gemmA_kernel(
    const u16* __restrict__ xnorm, const u16* __restrict__ W1b,
    const u16* __restrict__ xbf, const u16* __restrict__ owT,
    const int* __restrict__ bucket_rows, const int* __restrict__ small,
    const float* __restrict__ b1, const u16* __restrict__ zeropage,
    u16* __restrict__ a_buf, float* __restrict__ y)
{
    constexpr int KD = 512;
    __shared__ __align__(16) u16 As[2][128 * 32];
    __shared__ __align__(16) u16 Bs[2][256 * 32];

    int tid = threadIdx.x;
    int wave = tid >> 6, lane = tid & 63;
    const int lrow = lane >> 2;                              // row within 16-row chunk
    const int kcol = (((lane & 3) ^ ((lane >> 3) & 3)) * 8); // pre-swizzled global col-group
    int wm = (wave >> 2) * 64, wn = (wave & 3) * 64;         // wave -> 64x64 of 128x256
    int fr = lane & 15, kq = lane >> 4;
    const int kg = ((kq ^ ((fr >> 1) & 3)) * 8);             // swizzled read group

    bool m0 = blockIdx.y < 4;
    int base, bn, e = 0;
    const u16 *ga0, *gb0, *gb1;
    if (m0) {
        base = blockIdx.x * 128;
        if (base >= small[SM_AOFF + 8]) return;
        while (e < 7 && base >= small[SM_AOFF + e + 1]) ++e;
        bn = blockIdx.y * 256;
        int r0 = bucket_rows[base + wave * 16 + lrow];
        ga0 = ((r0 < 0) ? zeropage : xnorm + (size_t)r0 * KD) + kcol;
        const u16* Bsel = W1b + (size_t)e * HDIM * KD;
        gb0 = Bsel + (size_t)(bn + wave * 32 + lrow) * KD + kcol;
        gb1 = Bsel + (size_t)(bn + wave * 32 + 16 + lrow) * KD + kcol;
    } else {
        int j = blockIdx.x;
        if (j >= 128) return;
        base = (j >> 1) * 128;
        bn = (j & 1) * 256;
        ga0 = xbf + (size_t)(base + wave * 16 + lrow) * KD + kcol;
        gb0 = owT + (size_t)(bn + wave * 32 + lrow) * KD + kcol;
        gb1 = owT + (size_t)(bn + wave * 32 + 16 + lrow) * KD + kcol;
    }
    const int ofA = (wave * 16) * 32;
    const int ofB0 = (wave * 32) * 32;
    const int ofB1 = (wave * 32 + 16) * 32;

    float4v acc[4][4];
#pragma unroll
    for (int i = 0; i < 4; i++)
#pragma unroll
        for (int j = 0; j < 4; j++) acc[i][j] = (float4v){0.f, 0.f, 0.f, 0.f};

    constexpr int nk = KD >> 5; // 16
    async_copy16(&As[0][ofA], ga0);
    async_copy16(&Bs[0][ofB0], gb0);
    async_copy16(&Bs[0][ofB1], gb1);
    __syncthreads();

    int cur = 0;
    for (int t = 0; t < nk; ++t) {
        int nxt = cur ^ 1;
        if (t + 1 < nk) { // prefetch next tile; in flight across compute
            int k1 = (t + 1) << 5;
            async_copy16(&As[nxt][ofA], ga0 + k1);
            async_copy16(&Bs[nxt][ofB0], gb0 + k1);
            async_copy16(&Bs[nxt][ofB1], gb1 + k1);
        }
        short8 af[4], bf[4];
#pragma unroll
        for (int mt = 0; mt < 4; mt++) af[mt] = *(const short8*)&As[cur][(wm + mt * 16 + fr) * 32 + kg];
#pragma unroll
        for (int nt = 0; nt < 4; nt++) bf[nt] = *(const short8*)&Bs[cur][(wn + nt * 16 + fr) * 32 + kg];
#pragma unroll
        for (int mt = 0; mt < 4; mt++)
#pragma unroll
            for (int nt = 0; nt < 4; nt++)
                acc[mt][nt] = __builtin_amdgcn_mfma_f32_16x16x32_bf16(af[mt], bf[nt], acc[mt][nt], 0, 0, 0);
        __syncthreads();
        cur = nxt;
    }

    int rbase = (lane >> 4) * 4, c16 = lane & 15;
    if (m0) {
#pragma unroll
        for (int nt = 0; nt < 4; nt++) {
            int gn = bn + wn + nt * 16 + c16;
            float bv = b1[e * HDIM + gn];
#pragma unroll
            for (int mt = 0; mt < 4; mt++) {
                int gm = base + wm + mt * 16 + rbase;
#pragma unroll
                for (int r = 0; r < 4; r++) {
                    float h = acc[mt][nt][r] + bv;
                    float a = h * __builtin_amdgcn_rcpf(1.f + __expf(-h)); // fast SiLU
                    a_buf[(size_t)(gm + r) * HDIM + gn] = f2bf(a);
                }
            }
        }
    } else {
#pragma unroll
        for (int mt = 0; mt < 4; mt++) {
            int gm = base + wm + mt * 16 + rbase;
#pragma unroll
            for (int nt = 0; nt < 4; nt++) {
                int gn = bn + wn + nt * 16 + c16;
#pragma unroll
                for (int r = 0; r < 4; r++)
                    y[(size_t)(gm + r) * ODIM + gn] = acc[mt][nt][r];
            }
        }
    }
}

// ---------------- gemmB: expert down-proj, DENSE PLAIN STORES (R9-identical) ----------------
__global__ __launch_bounds__(512) void gemmB_kernel(
    const u16* __restrict__ a_buf, const u16* __restrict__ W2b,
    const int* __restrict__ bucket_rows, const int* __restrict__ small,
    const float* __restrict__ b2, const float* __restrict__ gate_by_pos,
    float* __restrict__ ye)
{
    constexpr int KD = 1024;
    __shared__ __align__(16) u16 As[2][128 * 32];
    __shared__ __align__(16) u16 Bs[2][256 * 32];

    int tid = threadIdx.x;
    int wave = tid >> 6, lane = tid & 63;
    const int lrow = lane >> 2;                              // row within 16-row chunk
    const int kcol = (((lane & 3) ^ ((lane >> 3) & 3)) * 8); // pre-swizzled global col-group
    int wm = (wave >> 2) * 64, wn = (wave & 3) * 64;         // wave -> 64x64 of 128x256
    int fr = lane & 15, kq = lane >> 4;
    const int kg = ((kq ^ ((fr >> 1) & 3)) * 8);             // swizzled read group

    int base = blockIdx.x * 128;
    if (base >= small[SM_AOFF + 8]) return;
    int e = 0;
    while (e < 7 && base >= small[SM_AOFF + e + 1]) ++e;
    int bn = blockIdx.y * 256;

    const u16* ga0 = a_buf + (size_t)(base + wave * 16 + lrow) * KD + kcol;
    const u16* Bsel = W2b + (size_t)e * ODIM * KD;
    const u16* gb0 = Bsel + (size_t)(bn + wave * 32 + lrow) * KD + kcol;
    const u16* gb1 = Bsel + (size_t)(bn + wave * 32 + 16 + lrow) * KD + kcol;
    const int ofA = (wave * 16) * 32;
    const int ofB0 = (wave * 32) * 32;
    const int ofB1 = (wave * 32 + 16) * 32;

    float4v acc[4][4];
#pragma unroll
    for (int i = 0; i < 4; i++)
#pragma unroll
        for (int j = 0; j < 4; j++) acc[i][j] = (float4v){0.f, 0.f, 0.f, 0.f};

    constexpr int nk = KD >> 5; // 32
    async_copy16(&As[0][ofA], ga0);
    async_copy16(&Bs[0][ofB0], gb0);
    async_copy16(&Bs[0][ofB1], gb1);
    __syncthreads();

    int cur = 0;
    for (int t = 0; t < nk; ++t) {
        int nxt = cur ^ 1;
        if (t + 1 < nk) { // prefetch next tile; in flight across compute
            int k1 = (t + 1) << 5;
            async_copy16(&As[nxt][ofA], ga0 + k1);
            async_copy16(&Bs[nxt][ofB0], gb0 + k1);
            async_copy16(&Bs[nxt][ofB1], gb1 + k1);
        }
        short8 af[4], bf[4];
#pragma unroll
        for (int mt = 0; mt < 4; mt++) af[mt] = *(const short8*)&As[cur][(wm + mt * 16 + fr) * 32 + kg];
#pragma unroll
        for (int nt = 0; nt < 4; nt++) bf[nt] = *(const short8*)&Bs[cur][(wn + nt * 16 + fr) * 32 + kg];
#pragma unroll
        for (int mt = 0; mt < 4; mt++)
#pragma unroll
            for (int nt = 0; nt < 4; nt++)
                acc[mt][nt] = __builtin_amdgcn_mfma_f32_16x16x32_bf16(af[mt], bf[nt], acc[mt][nt], 0, 0, 0);
        __syncthreads();
        cur = nxt;
    }

    int rbase = (lane >> 4) * 4, c16 = lane & 15;
#pragma unroll
    for (int mt = 0; mt < 4; mt++) {
        int pos0 = base + wm + mt * 16 + rbase;
        int rows[4]; float gs[4];
#pragma unroll
        for (int r = 0; r < 4; r++) { rows[r] = bucket_rows[pos0 + r]; gs[r] = gate_by_pos[pos0 + r]; }
#pragma unroll
        for (int nt = 0; nt < 4; nt++) {
            int gn = bn + wn + nt * 16 + c16;
            float b2v = b2[e * ODIM + gn];
#pragma unroll
            for (int r = 0; r < 4; r++) {
                if (rows[r] >= 0)
                    ye[(size_t)(pos0 + r) * ODIM + gn] = gs[r] * (acc[mt][nt][r] + b2v);
            }
        }
    }
}

// ---------------- combine: y[row] = y_mode2[row] + ye[pos0] + ye[pos1] ----------------
__global__ __launch_bounds__(256) void combine_kernel(
    const float* __restrict__ ye, const int* __restrict__ rowpos,
    float* __restrict__ y)
{
    int tid = threadIdx.x;
    int row = blockIdx.x * 16 + (tid >> 4);
    int c0 = (tid & 15) * 32;
    int p0 = rowpos[row * 2];
    int p1 = rowpos[row * 2 + 1];
    const float4* e0 = (const float4*)(ye + (size_t)p0 * ODIM + c0);
    const float4* e1 = (const float4*)(ye + (size_t)p1 * ODIM + c0);
    float4* yp = (float4*)(y + (size_t)row * ODIM + c0);
#pragma unroll
    for (int i = 0; i < 8; i++) {
        float4 a = yp[i], b = e0[i], c = e1[i];
        a.x += b.x + c.x; a.y += b.y + c.y; a.z += b.z + c.z; a.w += b.w + c.w;
        yp[i] = a;
    }
}

extern "C" void kernel_launch(void* const* d_in, const int* in_sizes, int n_in,
                              void* d_out, int out_size, void* d_ws, size_t ws_size,
                              hipStream_t stream)
{
    (void)in_sizes; (void)n_in; (void)out_size; (void)ws_size;
    const float* x = (const float*)d_in[0];
    // d_in[1] x_offsets, d_in[2] max_seq_len: unused by the reference math
    const float* noise = (const float*)d_in[3];
    const float* norm_w = (const float*)d_in[4];
    const float* norm_b = (const float*)d_in[5];
    const float* w_gate = (const float*)d_in[6];
    const float* w_noise = (const float*)d_in[7];
    const float* W1 = (const float*)d_in[8];
    const float* b1 = (const float*)d_in[9];
    const float* W2 = (const float*)d_in[10];
    const float* b2 = (const float*)d_in[11];
    const float* ow = (const float*)d_in[12];

    float* y = (float*)d_out;
    float* out_loss = y + (size_t)N_ROWS * ODIM;
    float* out_load = out_loss + 1;

    char* ws = (char*)d_ws;
    size_t off = 0;
    auto alloc = [&](size_t b) { size_t p = off; off = (off + b + 255) & ~(size_t)255; return p; };
    u16* xnorm_bf = (u16*)(ws + alloc((size_t)N_ROWS * DDIM * 2));
    u16* x_bf     = (u16*)(ws + alloc((size_t)N_ROWS * DDIM * 2));
    u16* W1b      = (u16*)(ws + alloc((size_t)NEXP * HDIM * DDIM * 2));
    u16* W2b      = (u16*)(ws + alloc((size_t)NEXP * ODIM * HDIM * 2));
    u16* owT      = (u16*)(ws + alloc((size_t)DDIM * ODIM * 2));
    u16* a_buf    = (u16*)(ws + alloc((size_t)MAXPOS * HDIM * 2));
    float* ye     = (float*)(ws + alloc((size_t)MAXPOS * ODIM * 4));
    int* pair_expert = (int*)(ws + alloc((size_t)MAXPAIRS * 4));
    float* pair_gate = (float*)(ws + alloc((size_t)MAXPAIRS * 4));
    float* gate_by_pos = (float*)(ws + alloc((size_t)MAXPOS * 4));
    int* bucket_rows = (int*)(ws + alloc((size_t)MAXPOS * 4));
    int* rowpos      = (int*)(ws + alloc((size_t)MAXPAIRS * 4));
    int* small       = (int*)(ws + alloc(SM_WORDS * 4));
    float* zeropage  = (float*)(ws + alloc(2048));
    float* partial_g = (float*)(ws + alloc((size_t)MEGA_GATE * NEXP * 4));
    float* partial_l = (float*)(ws + alloc((size_t)MEGA_GATE * NEXP * 4));
    int* partial_c   = (int*)(ws + alloc((size_t)MEGA_GATE * NEXP * 4));

    mega_kernel<<<MEGA_BLOCKS, 256, 0, stream>>>(
        x, noise, norm_w, norm_b, w_gate, w_noise, W1, ow, W2,
        xnorm_bf, x_bf, pair_expert, pair_gate, W1b, owT, W2b,
        bucket_rows, small, zeropage, partial_g, partial_l, partial_c);
    scatter_kernel<<<MAXPAIRS / 256, 256, 0, stream>>>(pair_expert, pair_gate,
                                                       partial_g, partial_l, partial_c,
                                                       small, bucket_rows, gate_by_pos, rowpos,
                                                       out_loss, out_load);
    gemmA_kernel<<<dim3(MAXTILES, 5), 512, 0, stream>>>(xnorm_bf, W1b,
                                                        x_bf, owT, bucket_rows, small, b1,
                                                        (const u16*)zeropage, a_buf, y);
    gemmB_kernel<<<dim3(MAXTILES, 2), 512, 0, stream>>>(a_buf, W2b, bucket_rows,
                                                        small, b2, gate_by_pos, ye);
    combine_kernel<<<N_ROWS / 16, 256, 0, stream>>>(ye, rowpos, y);
}